// Round 1
// baseline (33463.968 us; speedup 1.0000x reference)
//
#include <hip/hip_runtime.h>
#include <hip/hip_bf16.h>
#include <math.h>

// Problem constants
#define B_  16
#define T_  1023
#define C_  384
#define H_  6
#define DH_ 64
#define L_  6
#define V_  256
#define FF_ 1536
#define M_  (B_*T_)      // 16368 rows
#define EPS_ 1e-5f

// ---------------- embedding: h = tok_emb[x] + pos_emb ----------------
__global__ void embed_kernel(const int* __restrict__ x, const float* __restrict__ tok,
                             const float* __restrict__ pos, float* __restrict__ h) {
    int i = blockIdx.x * 256 + threadIdx.x;
    if (i >= M_ * C_) return;
    int bt = i / C_;
    int c  = i - bt * C_;
    int t  = bt % T_;
    h[i] = tok[x[bt] * C_ + c] + pos[t * C_ + c];
}

// ---------------- LayerNorm: one wave (64 lanes) per row of C=384 ----------------
__global__ __launch_bounds__(64) void ln_kernel(const float* __restrict__ in,
                                                const float* __restrict__ g,
                                                const float* __restrict__ b,
                                                float* __restrict__ out) {
    int row  = blockIdx.x;
    int lane = threadIdx.x;
    const float* rp = in + (size_t)row * C_;
    float v[6];
    float s = 0.f, s2 = 0.f;
#pragma unroll
    for (int i = 0; i < 6; ++i) {
        v[i] = rp[i * 64 + lane];
        s  += v[i];
        s2 += v[i] * v[i];
    }
#pragma unroll
    for (int o = 32; o > 0; o >>= 1) {
        s  += __shfl_xor(s,  o, 64);
        s2 += __shfl_xor(s2, o, 64);
    }
    float mu  = s * (1.0f / C_);
    float var = s2 * (1.0f / C_) - mu * mu;
    float rs  = rsqrtf(var + EPS_);
    float* op = out + (size_t)row * C_;
#pragma unroll
    for (int i = 0; i < 6; ++i) {
        int c = i * 64 + lane;
        op[c] = (v[i] - mu) * rs * g[c] + b[c];
    }
}

// ---------------- fp32 GEMM: out = [res +] relu?(A@W + bias) ----------------
// A: [M,K], W: [K,N], tile 64x64, 256 threads, 4x4 per thread, K-tile 16.
template<bool RELU, bool HAS_RES>
__global__ __launch_bounds__(256) void gemm_kernel(const float* __restrict__ A,
                                                   const float* __restrict__ W,
                                                   const float* __restrict__ bias,
                                                   const float* __restrict__ res,
                                                   float* __restrict__ out,
                                                   int M, int N, int K) {
    __shared__ float As[64][17];   // +1 pad: avoid bank conflicts on As[ty*4+ii][kk]
    __shared__ float Ws[16][64];
    int tid = threadIdx.x;
    int tx = tid & 15, ty = tid >> 4;
    int row0 = blockIdx.x * 64;
    int col0 = blockIdx.y * 64;

    int ai = tid >> 2;        // 0..63 : A-tile row
    int ak = (tid & 3) * 4;   // k offset within tile
    int wk = tid >> 4;        // 0..15 : W-tile k row
    int wj = (tid & 15) * 4;  // col offset

    float acc[4][4] = {};

    for (int k0 = 0; k0 < K; k0 += 16) {
        int arow = row0 + ai;
        if (arow < M) {
            const float* ap = A + (size_t)arow * K + k0 + ak;
#pragma unroll
            for (int q = 0; q < 4; ++q) As[ai][ak + q] = ap[q];
        } else {
#pragma unroll
            for (int q = 0; q < 4; ++q) As[ai][ak + q] = 0.f;
        }
        const float* wp = W + (size_t)(k0 + wk) * N + col0 + wj;
#pragma unroll
        for (int q = 0; q < 4; ++q) Ws[wk][wj + q] = wp[q];
        __syncthreads();

#pragma unroll
        for (int kk = 0; kk < 16; ++kk) {
            float a[4], w[4];
#pragma unroll
            for (int ii = 0; ii < 4; ++ii) a[ii] = As[ty * 4 + ii][kk];
#pragma unroll
            for (int jj = 0; jj < 4; ++jj) w[jj] = Ws[kk][tx * 4 + jj];
#pragma unroll
            for (int ii = 0; ii < 4; ++ii)
#pragma unroll
                for (int jj = 0; jj < 4; ++jj)
                    acc[ii][jj] += a[ii] * w[jj];
        }
        __syncthreads();
    }

#pragma unroll
    for (int ii = 0; ii < 4; ++ii) {
        int row = row0 + ty * 4 + ii;
        if (row >= M) continue;
#pragma unroll
        for (int jj = 0; jj < 4; ++jj) {
            int col = col0 + tx * 4 + jj;
            float val = acc[ii][jj];
            if (bias) val += bias[col];
            if (RELU) val = fmaxf(val, 0.0f);
            if (HAS_RES) val += res[(size_t)row * N + col];
            out[(size_t)row * N + col] = val;
        }
    }
}

// ---------------- flash attention (fp32, online softmax) ----------------
// grid: (16 q-tiles, B*H). block: 64 threads; thread = one query row.
__global__ __launch_bounds__(64) void attn_kernel(const float* __restrict__ q,
                                                  const float* __restrict__ k,
                                                  const float* __restrict__ v,
                                                  float* __restrict__ o) {
    __shared__ float Ks[64][65];
    __shared__ float Vs[64][65];
    int lane = threadIdx.x;
    int qt = blockIdx.x;
    int bh = blockIdx.y;
    int b  = bh / H_, hh = bh - b * H_;
    size_t base = (size_t)b * T_ * C_ + (size_t)hh * DH_;
    int t = qt * 64 + lane;
    bool vq = (t < T_);

    // stage Q tile (coalesced) then read own row
    for (int r = 0; r < 64; ++r) {
        int tt = qt * 64 + r;
        Ks[r][lane] = (tt < T_) ? q[base + (size_t)tt * C_ + lane] : 0.f;
    }
    __syncthreads();
    float qreg[64];
#pragma unroll
    for (int d = 0; d < 64; ++d) qreg[d] = Ks[lane][d];
    __syncthreads();

    float m = -INFINITY, l = 0.0f;
    float acc[64];
#pragma unroll
    for (int d = 0; d < 64; ++d) acc[d] = 0.f;

    for (int st = 0; st <= qt; ++st) {
        int s0 = st * 64;
        for (int r = 0; r < 64; ++r) {
            int ss = s0 + r;
            if (ss < T_) {
                Ks[r][lane] = k[base + (size_t)ss * C_ + lane];
                Vs[r][lane] = v[base + (size_t)ss * C_ + lane];
            } else {
                Ks[r][lane] = 0.f; Vs[r][lane] = 0.f;
            }
        }
        __syncthreads();

        if (vq) {
            int smax = t - s0 + 1;       // causal bound within this tile
            if (smax > 64) smax = 64;
            for (int s = 0; s < smax; ++s) {
                float sc = 0.f;
#pragma unroll
                for (int d = 0; d < 64; ++d) sc += qreg[d] * Ks[s][d];
                sc *= 0.125f;            // DH^-0.5
                float mn   = fmaxf(m, sc);
                float corr = __expf(m - mn);   // m=-inf first iter -> 0
                float p    = __expf(sc - mn);
                l = l * corr + p;
#pragma unroll
                for (int d = 0; d < 64; ++d) acc[d] = acc[d] * corr + p * Vs[s][d];
                m = mn;
            }
        }
        __syncthreads();
    }

    // write out via LDS for coalescing
    float inv = (l > 0.f) ? 1.0f / l : 0.f;
#pragma unroll
    for (int d = 0; d < 64; ++d) Ks[lane][d] = acc[d] * inv;
    __syncthreads();
    for (int r = 0; r < 64; ++r) {
        int tt = qt * 64 + r;
        if (tt < T_) o[base + (size_t)tt * C_ + lane] = Ks[r][lane];
    }
}

// ---------------- per-row NLL: one wave per row of V=256 ----------------
__global__ __launch_bounds__(64) void nll_kernel(const float* __restrict__ logits,
                                                 const int* __restrict__ tgt,
                                                 float* __restrict__ nll) {
    int row  = blockIdx.x;
    int lane = threadIdx.x;
    const float* rp = logits + (size_t)row * V_;
    float v[4];
    float mx = -INFINITY;
#pragma unroll
    for (int i = 0; i < 4; ++i) {
        v[i] = rp[i * 64 + lane];
        mx = fmaxf(mx, v[i]);
    }
#pragma unroll
    for (int o = 32; o > 0; o >>= 1) mx = fmaxf(mx, __shfl_xor(mx, o, 64));
    float s = 0.f;
#pragma unroll
    for (int i = 0; i < 4; ++i) s += expf(v[i] - mx);
#pragma unroll
    for (int o = 32; o > 0; o >>= 1) s += __shfl_xor(s, o, 64);
    if (lane == 0) {
        float lse = mx + logf(s);
        nll[row] = lse - rp[tgt[row]];
    }
}

// ---------------- final deterministic mean reduce ----------------
__global__ __launch_bounds__(256) void loss_kernel(const float* __restrict__ nll,
                                                   float* __restrict__ loss) {
    __shared__ float sm[256];
    float s = 0.f;
    for (int i = threadIdx.x; i < M_; i += 256) s += nll[i];
    sm[threadIdx.x] = s;
    __syncthreads();
    for (int o = 128; o > 0; o >>= 1) {
        if (threadIdx.x < o) sm[threadIdx.x] += sm[threadIdx.x + o];
        __syncthreads();
    }
    if (threadIdx.x == 0) *loss = sm[0] * (1.0f / M_);
}

// ---------------- host launcher ----------------
extern "C" void kernel_launch(void* const* d_in, const int* in_sizes, int n_in,
                              void* d_out, int out_size, void* d_ws, size_t ws_size,
                              hipStream_t stream) {
    const int*   x       = (const int*)d_in[0];
    const int*   targets = (const int*)d_in[1];
    const float* tok_emb = (const float*)d_in[2];
    const float* pos_emb = (const float*)d_in[3];
    const float* Wq      = (const float*)d_in[4];
    const float* Wk      = (const float*)d_in[5];
    const float* Wv      = (const float*)d_in[6];
    const float* Wo      = (const float*)d_in[7];
    const float* bo      = (const float*)d_in[8];
    const float* ln1_g   = (const float*)d_in[9];
    const float* ln1_b   = (const float*)d_in[10];
    const float* ln2_g   = (const float*)d_in[11];
    const float* ln2_b   = (const float*)d_in[12];
    const float* W1      = (const float*)d_in[13];
    const float* b1      = (const float*)d_in[14];
    const float* W2      = (const float*)d_in[15];
    const float* b2      = (const float*)d_in[16];
    const float* lnf_g   = (const float*)d_in[17];
    const float* lnf_b   = (const float*)d_in[18];
    const float* Wf      = (const float*)d_in[19];
    const float* bf      = (const float*)d_in[20];

    float* logits = (float*)d_out;                 // [M_, V_]
    float* loss   = logits + (size_t)M_ * V_;      // scalar

    // workspace carve-up (floats):
    //   h  : M_*C_
    //   z  : M_*C_
    //   big: M_*FF_  (time-shared: {q,k,v,o} during attention, ff during MLP)
    //   nll: M_
    float* ws  = (float*)d_ws;
    float* h   = ws;
    float* z   = h + (size_t)M_ * C_;
    float* big = z + (size_t)M_ * C_;
    float* qb  = big;
    float* kb  = big + (size_t)M_ * C_;
    float* vb  = big + 2 * (size_t)M_ * C_;
    float* ob  = big + 3 * (size_t)M_ * C_;
    float* ff  = big;
    float* nll = big + (size_t)M_ * FF_;

    dim3 gemm_blk(256);
    dim3 g_cc((M_ + 63) / 64, C_ / 64);    // N=384
    dim3 g_cf((M_ + 63) / 64, FF_ / 64);   // N=1536
    dim3 g_cv((M_ + 63) / 64, V_ / 64);    // N=256

    embed_kernel<<<(M_ * C_ + 255) / 256, 256, 0, stream>>>(x, tok_emb, pos_emb, h);

    for (int l = 0; l < L_; ++l) {
        const float* wq = Wq + (size_t)l * C_ * C_;
        const float* wk = Wk + (size_t)l * C_ * C_;
        const float* wv = Wv + (size_t)l * C_ * C_;
        const float* wo = Wo + (size_t)l * C_ * C_;
        const float* w1 = W1 + (size_t)l * C_ * FF_;
        const float* w2 = W2 + (size_t)l * FF_ * C_;

        // z = LN1(h)
        ln_kernel<<<M_, 64, 0, stream>>>(h, ln1_g + l * C_, ln1_b + l * C_, z);
        // q,k,v = z @ W{q,k,v}
        gemm_kernel<false, false><<<g_cc, gemm_blk, 0, stream>>>(z, wq, nullptr, nullptr, qb, M_, C_, C_);
        gemm_kernel<false, false><<<g_cc, gemm_blk, 0, stream>>>(z, wk, nullptr, nullptr, kb, M_, C_, C_);
        gemm_kernel<false, false><<<g_cc, gemm_blk, 0, stream>>>(z, wv, nullptr, nullptr, vb, M_, C_, C_);
        // o = attention(q,k,v)
        attn_kernel<<<dim3(16, B_ * H_), 64, 0, stream>>>(qb, kb, vb, ob);
        // h = h + o @ Wo + bo
        gemm_kernel<false, true><<<g_cc, gemm_blk, 0, stream>>>(ob, wo, bo + l * C_, h, h, M_, C_, C_);
        // z = LN2(h)
        ln_kernel<<<M_, 64, 0, stream>>>(h, ln2_g + l * C_, ln2_b + l * C_, z);
        // ff = relu(z @ W1 + b1)
        gemm_kernel<true, false><<<g_cf, gemm_blk, 0, stream>>>(z, w1, b1 + l * FF_, nullptr, ff, M_, FF_, C_);
        // h = h + ff @ W2 + b2
        gemm_kernel<false, true><<<g_cc, gemm_blk, 0, stream>>>(ff, w2, b2 + l * C_, h, h, M_, C_, FF_);
    }

    // final LN + projection
    ln_kernel<<<M_, 64, 0, stream>>>(h, lnf_g, lnf_b, z);
    gemm_kernel<false, false><<<g_cv, gemm_blk, 0, stream>>>(z, Wf, bf, nullptr, logits, M_, V_, C_);

    // loss
    nll_kernel<<<M_, 64, 0, stream>>>(logits, targets, nll);
    loss_kernel<<<1, 256, 0, stream>>>(nll, loss);
}

// Round 2
// 6108.347 us; speedup vs baseline: 5.4784x; 5.4784x over previous
//
#include <hip/hip_runtime.h>
#include <hip/hip_bf16.h>
#include <math.h>

// Problem constants
#define B_  16
#define T_  1023
#define C_  384
#define H_  6
#define DH_ 64
#define L_  6
#define V_  256
#define FF_ 1536
#define M_  (B_*T_)      // 16368 rows
#define EPS_ 1e-5f

typedef __attribute__((ext_vector_type(8))) short bf16x8;
typedef __attribute__((ext_vector_type(4))) short short4v;
typedef __attribute__((ext_vector_type(4))) float f32x4;

__device__ inline short f2bf(float x) {   // RNE float->bf16
    union { float f; unsigned u; } c; c.f = x;
    unsigned r = (c.u + 0x7fffu + ((c.u >> 16) & 1u)) >> 16;
    return (short)r;
}

// ---------------- embedding: h = tok_emb[x] + pos_emb ----------------
__global__ void embed_kernel(const int* __restrict__ x, const float* __restrict__ tok,
                             const float* __restrict__ pos, float* __restrict__ h) {
    int i = blockIdx.x * 256 + threadIdx.x;
    if (i >= M_ * C_) return;
    int bt = i / C_;
    int c  = i - bt * C_;
    int t  = bt % T_;
    h[i] = tok[x[bt] * C_ + c] + pos[t * C_ + c];
}

// ---------------- LayerNorm: one wave (64 lanes) per row of C=384 ----------------
__global__ __launch_bounds__(64) void ln_kernel(const float* __restrict__ in,
                                                const float* __restrict__ g,
                                                const float* __restrict__ b,
                                                float* __restrict__ out) {
    int row  = blockIdx.x;
    int lane = threadIdx.x;
    const float* rp = in + (size_t)row * C_;
    float v[6];
    float s = 0.f, s2 = 0.f;
#pragma unroll
    for (int i = 0; i < 6; ++i) {
        v[i] = rp[i * 64 + lane];
        s  += v[i];
        s2 += v[i] * v[i];
    }
#pragma unroll
    for (int o = 32; o > 0; o >>= 1) {
        s  += __shfl_xor(s,  o, 64);
        s2 += __shfl_xor(s2, o, 64);
    }
    float mu  = s * (1.0f / C_);
    float var = s2 * (1.0f / C_) - mu * mu;
    float rs  = rsqrtf(var + EPS_);
    float* op = out + (size_t)row * C_;
#pragma unroll
    for (int i = 0; i < 6; ++i) {
        int c = i * 64 + lane;
        op[c] = (v[i] - mu) * rs * g[c] + b[c];
    }
}

// ---------------- fp32 GEMM: out = [res +] relu?(A@W + bias) ----------------
template<bool RELU, bool HAS_RES>
__global__ __launch_bounds__(256) void gemm_kernel(const float* __restrict__ A,
                                                   const float* __restrict__ W,
                                                   const float* __restrict__ bias,
                                                   const float* __restrict__ res,
                                                   float* __restrict__ out,
                                                   int M, int N, int K) {
    __shared__ float As[64][17];
    __shared__ float Ws[16][64];
    int tid = threadIdx.x;
    int tx = tid & 15, ty = tid >> 4;
    int row0 = blockIdx.x * 64;
    int col0 = blockIdx.y * 64;

    int ai = tid >> 2;
    int ak = (tid & 3) * 4;
    int wk = tid >> 4;
    int wj = (tid & 15) * 4;

    float acc[4][4] = {};

    for (int k0 = 0; k0 < K; k0 += 16) {
        int arow = row0 + ai;
        if (arow < M) {
            const float* ap = A + (size_t)arow * K + k0 + ak;
#pragma unroll
            for (int q = 0; q < 4; ++q) As[ai][ak + q] = ap[q];
        } else {
#pragma unroll
            for (int q = 0; q < 4; ++q) As[ai][ak + q] = 0.f;
        }
        const float* wp = W + (size_t)(k0 + wk) * N + col0 + wj;
#pragma unroll
        for (int q = 0; q < 4; ++q) Ws[wk][wj + q] = wp[q];
        __syncthreads();

#pragma unroll
        for (int kk = 0; kk < 16; ++kk) {
            float a[4], w[4];
#pragma unroll
            for (int ii = 0; ii < 4; ++ii) a[ii] = As[ty * 4 + ii][kk];
#pragma unroll
            for (int jj = 0; jj < 4; ++jj) w[jj] = Ws[kk][tx * 4 + jj];
#pragma unroll
            for (int ii = 0; ii < 4; ++ii)
#pragma unroll
                for (int jj = 0; jj < 4; ++jj)
                    acc[ii][jj] += a[ii] * w[jj];
        }
        __syncthreads();
    }

#pragma unroll
    for (int ii = 0; ii < 4; ++ii) {
        int row = row0 + ty * 4 + ii;
        if (row >= M) continue;
#pragma unroll
        for (int jj = 0; jj < 4; ++jj) {
            int col = col0 + tx * 4 + jj;
            float val = acc[ii][jj];
            if (bias) val += bias[col];
            if (RELU) val = fmaxf(val, 0.0f);
            if (HAS_RES) val += res[(size_t)row * N + col];
            out[(size_t)row * N + col] = val;
        }
    }
}

// ---------------- MFMA flash attention (bf16 inputs, fp32 accum) ----------------
// grid: (16 q-tiles, B*H). block: 256 threads = 4 waves; wave w owns q rows
// q0+16w .. q0+16w+15. K/V tiles of 32 keys staged in LDS as bf16.
// Swapped QK^T: S^T = K @ Q^T so each lane's scores belong to ONE query.
__global__ __launch_bounds__(256) void attn_kernel(const float* __restrict__ q,
                                                   const float* __restrict__ k,
                                                   const float* __restrict__ v,
                                                   float* __restrict__ o) {
    __shared__ short K_lds[32][72];        // [key][dh], bf16, pad to 144B rows
    __shared__ short V_lds[64][40];        // V^T: [dh][key], pad to 80B rows
    __shared__ short P_lds[4][16][40];     // per-wave P[q][key] bf16
    __shared__ float O_lds[4][16][66];     // per-wave O[q][dh] f32 staging

    int tid  = threadIdx.x;
    int wave = tid >> 6;
    int lane = tid & 63;
    int g    = lane >> 4;      // k-octet group
    int r16  = lane & 15;

    int qt = blockIdx.x;
    int bh = blockIdx.y;
    int b  = bh / H_, hh = bh - b * H_;
    size_t base = (size_t)b * T_ * C_ + hh * DH_;

    int q0 = qt * 64;
    int qg = q0 + wave * 16 + r16;         // this lane's global q row

    // Q fragments (B operand of S^T): qf[half][i] = Q[qg][32*half+8g+i] * 1/8
    bf16x8 qf0, qf1;
    {
        const float* qp = q + base + (size_t)qg * C_ + 8 * g;
#pragma unroll
        for (int i = 0; i < 8; ++i) qf0[i] = f2bf(qp[i] * 0.125f);
        qp += 32;
#pragma unroll
        for (int i = 0; i < 8; ++i) qf1[i] = f2bf(qp[i] * 0.125f);
    }

    f32x4 o_acc[4];
#pragma unroll
    for (int d = 0; d < 4; ++d) { o_acc[d][0] = 0.f; o_acc[d][1] = 0.f; o_acc[d][2] = 0.f; o_acc[d][3] = 0.f; }
    float m = -3e38f, l = 0.f;

    int skey = tid >> 3;               // staging: key 0..31
    int sd0  = (tid & 7) * 8;          // staging: dh octet
    int kt_hi = (q0 + wave * 16 + 15) >> 5;
    int nkt = 2 * (qt + 1);

    for (int kt = 0; kt < nkt; ++kt) {
        __syncthreads();
        // ---- stage K tile + transposed V tile (fp32 -> bf16) ----
        int ss = kt * 32 + skey;
        float kv8[8], vv8[8];
        if (ss < T_) {
            const float* kp = k + base + (size_t)ss * C_ + sd0;
            const float* vp = v + base + (size_t)ss * C_ + sd0;
#pragma unroll
            for (int i = 0; i < 8; ++i) { kv8[i] = kp[i]; vv8[i] = vp[i]; }
        } else {
#pragma unroll
            for (int i = 0; i < 8; ++i) { kv8[i] = 0.f; vv8[i] = 0.f; }
        }
        bf16x8 kbv;
#pragma unroll
        for (int i = 0; i < 8; ++i) kbv[i] = f2bf(kv8[i]);
        *(bf16x8*)&K_lds[skey][sd0] = kbv;
#pragma unroll
        for (int i = 0; i < 8; ++i) V_lds[sd0 + i][skey] = f2bf(vv8[i]);
        __syncthreads();

        if (kt > kt_hi) continue;      // no work for this wave; barriers stay aligned

        // ---- S^T = K @ Q^T : two 16-key fragments ----
        f32x4 s0, s1;
        s0[0]=0.f;s0[1]=0.f;s0[2]=0.f;s0[3]=0.f;
        s1[0]=0.f;s1[1]=0.f;s1[2]=0.f;s1[3]=0.f;
        {
            bf16x8 a00 = *(const bf16x8*)&K_lds[r16][8 * g];
            bf16x8 a01 = *(const bf16x8*)&K_lds[r16][32 + 8 * g];
            bf16x8 a10 = *(const bf16x8*)&K_lds[16 + r16][8 * g];
            bf16x8 a11 = *(const bf16x8*)&K_lds[16 + r16][32 + 8 * g];
            s0 = __builtin_amdgcn_mfma_f32_16x16x32_bf16(a00, qf0, s0, 0, 0, 0);
            s0 = __builtin_amdgcn_mfma_f32_16x16x32_bf16(a01, qf1, s0, 0, 0, 0);
            s1 = __builtin_amdgcn_mfma_f32_16x16x32_bf16(a10, qf0, s1, 0, 0, 0);
            s1 = __builtin_amdgcn_mfma_f32_16x16x32_bf16(a11, qf1, s1, 0, 0, 0);
        }

        // ---- causal mask + online softmax (per lane: one q, 8 keys) ----
        int kb0 = kt * 32 + 4 * g;
        float sv[8];
#pragma unroll
        for (int r = 0; r < 4; ++r) {
            sv[r]     = (kb0 + r      <= qg) ? s0[r] : -3e38f;
            sv[4 + r] = (kb0 + 16 + r <= qg) ? s1[r] : -3e38f;
        }
        float pmax = sv[0];
#pragma unroll
        for (int i = 1; i < 8; ++i) pmax = fmaxf(pmax, sv[i]);
        pmax = fmaxf(pmax, __shfl_xor(pmax, 16, 64));
        pmax = fmaxf(pmax, __shfl_xor(pmax, 32, 64));
        float mn   = fmaxf(m, pmax);
        float corr = __expf(m - mn);
        float rs = 0.f;
        short pb[8];
#pragma unroll
        for (int i = 0; i < 8; ++i) {
            float p = __expf(sv[i] - mn);
            rs += p;
            pb[i] = f2bf(p);
        }
        rs += __shfl_xor(rs, 16, 64);
        rs += __shfl_xor(rs, 32, 64);
        l = l * corr + rs;
        m = mn;

        // write P (stored [q][key]); lane covers keys 4g+r and 16+4g+r
        short4v t0, t1;
        t0[0]=pb[0]; t0[1]=pb[1]; t0[2]=pb[2]; t0[3]=pb[3];
        t1[0]=pb[4]; t1[1]=pb[5]; t1[2]=pb[6]; t1[3]=pb[7];
        *(short4v*)&P_lds[wave][r16][4 * g]      = t0;
        *(short4v*)&P_lds[wave][r16][16 + 4 * g] = t1;

        // ---- O^T = O^T*corr + V^T @ P^T ----
#pragma unroll
        for (int d = 0; d < 4; ++d) {
            o_acc[d][0] *= corr; o_acc[d][1] *= corr;
            o_acc[d][2] *= corr; o_acc[d][3] *= corr;
        }
        bf16x8 pB = *(const bf16x8*)&P_lds[wave][r16][8 * g];
#pragma unroll
        for (int d = 0; d < 4; ++d) {
            bf16x8 vA = *(const bf16x8*)&V_lds[16 * d + r16][8 * g];
            o_acc[d] = __builtin_amdgcn_mfma_f32_16x16x32_bf16(vA, pB, o_acc[d], 0, 0, 0);
        }
    }

    // ---- normalize, stage to LDS, coalesced write ----
    float inv = (l > 0.f) ? 1.f / l : 0.f;
#pragma unroll
    for (int d = 0; d < 4; ++d)
#pragma unroll
        for (int r = 0; r < 4; ++r)
            O_lds[wave][r16][16 * d + 4 * g + r] = o_acc[d][r] * inv;
    // same-wave LDS read-after-write: ordered by lgkmcnt within the wave
    for (int rr = 0; rr < 16; ++rr) {
        int tt = q0 + wave * 16 + rr;
        if (tt < T_) o[base + (size_t)tt * C_ + lane] = O_lds[wave][rr][lane];
    }
}

// ---------------- per-row NLL ----------------
__global__ __launch_bounds__(64) void nll_kernel(const float* __restrict__ logits,
                                                 const int* __restrict__ tgt,
                                                 float* __restrict__ nll) {
    int row  = blockIdx.x;
    int lane = threadIdx.x;
    const float* rp = logits + (size_t)row * V_;
    float v[4];
    float mx = -INFINITY;
#pragma unroll
    for (int i = 0; i < 4; ++i) {
        v[i] = rp[i * 64 + lane];
        mx = fmaxf(mx, v[i]);
    }
#pragma unroll
    for (int o = 32; o > 0; o >>= 1) mx = fmaxf(mx, __shfl_xor(mx, o, 64));
    float s = 0.f;
#pragma unroll
    for (int i = 0; i < 4; ++i) s += expf(v[i] - mx);
#pragma unroll
    for (int o = 32; o > 0; o >>= 1) s += __shfl_xor(s, o, 64);
    if (lane == 0) {
        float lse = mx + logf(s);
        nll[row] = lse - rp[tgt[row]];
    }
}

// ---------------- final deterministic mean reduce ----------------
__global__ __launch_bounds__(256) void loss_kernel(const float* __restrict__ nll,
                                                   float* __restrict__ loss) {
    __shared__ float sm[256];
    float s = 0.f;
    for (int i = threadIdx.x; i < M_; i += 256) s += nll[i];
    sm[threadIdx.x] = s;
    __syncthreads();
    for (int o = 128; o > 0; o >>= 1) {
        if (threadIdx.x < o) sm[threadIdx.x] += sm[threadIdx.x + o];
        __syncthreads();
    }
    if (threadIdx.x == 0) *loss = sm[0] * (1.0f / M_);
}

// ---------------- host launcher ----------------
extern "C" void kernel_launch(void* const* d_in, const int* in_sizes, int n_in,
                              void* d_out, int out_size, void* d_ws, size_t ws_size,
                              hipStream_t stream) {
    const int*   x       = (const int*)d_in[0];
    const int*   targets = (const int*)d_in[1];
    const float* tok_emb = (const float*)d_in[2];
    const float* pos_emb = (const float*)d_in[3];
    const float* Wq      = (const float*)d_in[4];
    const float* Wk      = (const float*)d_in[5];
    const float* Wv      = (const float*)d_in[6];
    const float* Wo      = (const float*)d_in[7];
    const float* bo      = (const float*)d_in[8];
    const float* ln1_g   = (const float*)d_in[9];
    const float* ln1_b   = (const float*)d_in[10];
    const float* ln2_g   = (const float*)d_in[11];
    const float* ln2_b   = (const float*)d_in[12];
    const float* W1      = (const float*)d_in[13];
    const float* b1      = (const float*)d_in[14];
    const float* W2      = (const float*)d_in[15];
    const float* b2      = (const float*)d_in[16];
    const float* lnf_g   = (const float*)d_in[17];
    const float* lnf_b   = (const float*)d_in[18];
    const float* Wf      = (const float*)d_in[19];
    const float* bf      = (const float*)d_in[20];

    float* logits = (float*)d_out;
    float* loss   = logits + (size_t)M_ * V_;

    float* ws  = (float*)d_ws;
    float* h   = ws;
    float* z   = h + (size_t)M_ * C_;
    float* big = z + (size_t)M_ * C_;
    float* qb  = big;
    float* kb  = big + (size_t)M_ * C_;
    float* vb  = big + 2 * (size_t)M_ * C_;
    float* ob  = big + 3 * (size_t)M_ * C_;
    float* ff  = big;
    float* nll = big + (size_t)M_ * FF_;

    dim3 gemm_blk(256);
    dim3 g_cc((M_ + 63) / 64, C_ / 64);
    dim3 g_cf((M_ + 63) / 64, FF_ / 64);
    dim3 g_cv((M_ + 63) / 64, V_ / 64);

    embed_kernel<<<(M_ * C_ + 255) / 256, 256, 0, stream>>>(x, tok_emb, pos_emb, h);

    for (int l = 0; l < L_; ++l) {
        const float* wq = Wq + (size_t)l * C_ * C_;
        const float* wk = Wk + (size_t)l * C_ * C_;
        const float* wv = Wv + (size_t)l * C_ * C_;
        const float* wo = Wo + (size_t)l * C_ * C_;
        const float* w1 = W1 + (size_t)l * C_ * FF_;
        const float* w2 = W2 + (size_t)l * FF_ * C_;

        ln_kernel<<<M_, 64, 0, stream>>>(h, ln1_g + l * C_, ln1_b + l * C_, z);
        gemm_kernel<false, false><<<g_cc, gemm_blk, 0, stream>>>(z, wq, nullptr, nullptr, qb, M_, C_, C_);
        gemm_kernel<false, false><<<g_cc, gemm_blk, 0, stream>>>(z, wk, nullptr, nullptr, kb, M_, C_, C_);
        gemm_kernel<false, false><<<g_cc, gemm_blk, 0, stream>>>(z, wv, nullptr, nullptr, vb, M_, C_, C_);
        attn_kernel<<<dim3(16, B_ * H_), 256, 0, stream>>>(qb, kb, vb, ob);
        gemm_kernel<false, true><<<g_cc, gemm_blk, 0, stream>>>(ob, wo, bo + l * C_, h, h, M_, C_, C_);
        ln_kernel<<<M_, 64, 0, stream>>>(h, ln2_g + l * C_, ln2_b + l * C_, z);
        gemm_kernel<true, false><<<g_cf, gemm_blk, 0, stream>>>(z, w1, b1 + l * FF_, nullptr, ff, M_, FF_, C_);
        gemm_kernel<false, true><<<g_cc, gemm_blk, 0, stream>>>(ff, w2, b2 + l * C_, h, h, M_, C_, FF_);
    }

    ln_kernel<<<M_, 64, 0, stream>>>(h, lnf_g, lnf_b, z);
    gemm_kernel<false, false><<<g_cv, gemm_blk, 0, stream>>>(z, Wf, bf, nullptr, logits, M_, V_, C_);

    nll_kernel<<<M_, 64, 0, stream>>>(logits, targets, nll);
    loss_kernel<<<1, 256, 0, stream>>>(nll, loss);
}

// Round 3
// 1871.864 us; speedup vs baseline: 17.8774x; 3.2632x over previous
//
#include <hip/hip_runtime.h>
#include <hip/hip_bf16.h>
#include <math.h>

// Problem constants
#define B_  16
#define T_  1023
#define C_  384
#define H_  6
#define DH_ 64
#define L_  6
#define V_  256
#define FF_ 1536
#define M_  (B_*T_)      // 16368 rows
#define MP_ 16384        // padded rows (128-multiple)
#define EPS_ 1e-5f

typedef __attribute__((ext_vector_type(8))) short bf16x8;
typedef __attribute__((ext_vector_type(4))) short short4v;
typedef __attribute__((ext_vector_type(4))) float f32x4;

__device__ inline short f2bf(float x) {   // RNE float->bf16
    union { float f; unsigned u; } c; c.f = x;
    unsigned r = (c.u + 0x7fffu + ((c.u >> 16) & 1u)) >> 16;
    return (short)r;
}

#define GLDS16(g, l) __builtin_amdgcn_global_load_lds(                         \
    (const __attribute__((address_space(1))) void*)(g),                        \
    (__attribute__((address_space(3))) void*)(l), 16, 0, 0)

// ---------------- embedding: h = tok_emb[x] + pos_emb (fp32) ----------------
__global__ void embed_kernel(const int* __restrict__ x, const float* __restrict__ tok,
                             const float* __restrict__ pos, float* __restrict__ h) {
    int i = blockIdx.x * 256 + threadIdx.x;
    if (i >= M_ * C_) return;
    int bt = i / C_;
    int c  = i - bt * C_;
    int t  = bt % T_;
    h[i] = tok[x[bt] * C_ + c] + pos[t * C_ + c];
}

// ---------------- weight transpose+convert: src fp32 [K][N] -> dst bf16 [N][K] ----
__global__ __launch_bounds__(256) void wconv_kernel(
    const float* __restrict__ Wq, const float* __restrict__ Wk,
    const float* __restrict__ Wv, const float* __restrict__ Wo,
    const float* __restrict__ W1, const float* __restrict__ W2,
    const float* __restrict__ Wf,
    short* __restrict__ qkvt, short* __restrict__ wot, short* __restrict__ w1t,
    short* __restrict__ w2t, short* __restrict__ wft) {
    __shared__ float tile[32][33];
    int t = blockIdx.x;
    const float* src; short* dst; int K, N, tl;
    if (t < 10368) {
        int l = t / 1728, r = t - l * 1728;
        if (r < 432) {                 // Wq/Wk/Wv -> fused qkv^T rows
            int which = r / 144; tl = r - which * 144;
            src = (which == 0 ? Wq : which == 1 ? Wk : Wv) + (size_t)l * 384 * 384;
            dst = qkvt + (size_t)l * 1152 * 384 + (size_t)which * 384 * 384;
            K = 384; N = 384;
        } else if (r < 576) {
            tl = r - 432;
            src = Wo + (size_t)l * 384 * 384; dst = wot + (size_t)l * 384 * 384;
            K = 384; N = 384;
        } else if (r < 1152) {
            tl = r - 576;
            src = W1 + (size_t)l * 384 * 1536; dst = w1t + (size_t)l * 1536 * 384;
            K = 384; N = 1536;
        } else {
            tl = r - 1152;
            src = W2 + (size_t)l * 1536 * 384; dst = w2t + (size_t)l * 384 * 1536;
            K = 1536; N = 384;
        }
    } else {
        tl = t - 10368; src = Wf; dst = wft; K = 384; N = 256;
    }
    int ntx = N >> 5;
    int k0 = (tl / ntx) << 5, n0 = (tl % ntx) << 5;
    int rr = threadIdx.x >> 5, cc = threadIdx.x & 31;
#pragma unroll
    for (int p = 0; p < 4; ++p)
        tile[rr + 8 * p][cc] = src[(size_t)(k0 + rr + 8 * p) * N + n0 + cc];
    __syncthreads();
#pragma unroll
    for (int p = 0; p < 4; ++p)
        dst[(size_t)(n0 + rr + 8 * p) * K + k0 + cc] = f2bf(tile[cc][rr + 8 * p]);
}

// ---------------- LayerNorm: fp32 in -> bf16 out, one wave per row ----------------
__global__ __launch_bounds__(64) void ln_kernel(const float* __restrict__ in,
                                                const float* __restrict__ g,
                                                const float* __restrict__ b,
                                                short* __restrict__ out) {
    int row  = blockIdx.x;
    int lane = threadIdx.x;
    const float* rp = in + (size_t)row * C_;
    float v[6];
    float s = 0.f, s2 = 0.f;
#pragma unroll
    for (int i = 0; i < 6; ++i) {
        v[i] = rp[i * 64 + lane];
        s  += v[i];
        s2 += v[i] * v[i];
    }
#pragma unroll
    for (int o = 32; o > 0; o >>= 1) {
        s  += __shfl_xor(s,  o, 64);
        s2 += __shfl_xor(s2, o, 64);
    }
    float mu  = s * (1.0f / C_);
    float var = s2 * (1.0f / C_) - mu * mu;
    float rs  = rsqrtf(var + EPS_);
    short* op = out + (size_t)row * C_;
#pragma unroll
    for (int i = 0; i < 6; ++i) {
        int c = i * 64 + lane;
        op[c] = f2bf((v[i] - mu) * rs * g[c] + b[c]);
    }
}

// ---------------- bf16 MFMA GEMM: out = epilogue(A @ Bt^T) ----------------
// A: bf16 [MP_][K]; Bt: bf16 [N][K] (pre-transposed). 128x128 tile, BK=32,
// 256 threads = 4 waves (2x2 of 64x64), global_load_lds staging.
// MODE 0: bf16 store; MODE 1: fp32 in-place residual (outf += acc+bias);
// MODE 2: fp32 store, row<M_ guarded.
template<int MODE, bool RELU, bool HB>
__global__ __launch_bounds__(256) void mm_kernel(const short* __restrict__ A,
                                                 const short* __restrict__ Bt,
                                                 const float* __restrict__ bias,
                                                 short* __restrict__ outb,
                                                 float* __restrict__ outf,
                                                 int N, int K) {
    __shared__ short Al[4][128][8];   // [k-octet][row][8] : linear chunk c=kg*128+row
    __shared__ short Bl[4][128][8];   // [k-octet][col][8]
    int tid  = threadIdx.x;
    int wave = tid >> 6, lane = tid & 63;
    int kg4 = lane >> 4, r16 = lane & 15;
    int wr = (wave >> 1) * 64, wc = (wave & 1) * 64;
    int row0 = blockIdx.x * 128, col0 = blockIdx.y * 128;

    const short* ga = A  + (size_t)(row0 + (tid & 127)) * K + ((tid >> 7) << 3);
    const short* gb = Bt + (size_t)(col0 + (tid & 127)) * K + ((tid >> 7) << 3);
    short* la = &Al[0][0][0] + tid * 8;
    short* lb = &Bl[0][0][0] + tid * 8;

    f32x4 acc[4][4];
#pragma unroll
    for (int i = 0; i < 4; ++i)
#pragma unroll
        for (int j = 0; j < 4; ++j) { acc[i][j][0]=0.f; acc[i][j][1]=0.f; acc[i][j][2]=0.f; acc[i][j][3]=0.f; }

    for (int k0 = 0; k0 < K; k0 += 32) {
        GLDS16(ga, la);          GLDS16(ga + 16, la + 2048);
        GLDS16(gb, lb);          GLDS16(gb + 16, lb + 2048);
        ga += 32; gb += 32;
        __syncthreads();         // drains vmcnt before barrier

        bf16x8 av[4], bv[4];
#pragma unroll
        for (int i = 0; i < 4; ++i) av[i] = *(const bf16x8*)&Al[kg4][wr + 16 * i + r16][0];
#pragma unroll
        for (int j = 0; j < 4; ++j) bv[j] = *(const bf16x8*)&Bl[kg4][wc + 16 * j + r16][0];
#pragma unroll
        for (int i = 0; i < 4; ++i)
#pragma unroll
            for (int j = 0; j < 4; ++j)
                acc[i][j] = __builtin_amdgcn_mfma_f32_16x16x32_bf16(av[i], bv[j], acc[i][j], 0, 0, 0);
        __syncthreads();         // protect LDS from next-iter staging
    }

#pragma unroll
    for (int j = 0; j < 4; ++j) {
        int col = col0 + wc + 16 * j + r16;
        float bj = HB ? bias[col] : 0.f;
#pragma unroll
        for (int i = 0; i < 4; ++i) {
#pragma unroll
            for (int rg = 0; rg < 4; ++rg) {
                int row = row0 + wr + 16 * i + 4 * kg4 + rg;
                float v = acc[i][j][rg] + bj;
                if (RELU) v = fmaxf(v, 0.f);
                if (MODE == 0) {
                    outb[(size_t)row * N + col] = f2bf(v);
                } else if (MODE == 1) {
                    outf[(size_t)row * N + col] += v;
                } else {
                    if (row < M_) outf[(size_t)row * N + col] = v;
                }
            }
        }
    }
}

// ---------------- MFMA flash attention (bf16 qkv in, bf16 o out) ----------------
// qkv: [MP_][1152] rows b*T+t; q at col hh*64, k at 384+hh*64, v at 768+hh*64.
__global__ __launch_bounds__(256) void attn_kernel(const short* __restrict__ qkv,
                                                   short* __restrict__ o) {
    __shared__ short K_lds[32][72];
    __shared__ short V_lds[64][40];
    __shared__ short P_lds[4][16][40];
    __shared__ float O_lds[4][16][66];

    int tid  = threadIdx.x;
    int wave = tid >> 6;
    int lane = tid & 63;
    int g    = lane >> 4;
    int r16  = lane & 15;

    int qt = blockIdx.x;
    int bh = blockIdx.y;
    int b  = bh / H_, hh = bh - b * H_;
    size_t rbase = (size_t)b * T_;
    int qoff = hh * 64;

    int q0 = qt * 64;
    int qg = q0 + wave * 16 + r16;          // may be 1023 (pad row, masked out)

    bf16x8 qf0 = *(const bf16x8*)&qkv[(rbase + qg) * 1152 + qoff + 8 * g];
    bf16x8 qf1 = *(const bf16x8*)&qkv[(rbase + qg) * 1152 + qoff + 32 + 8 * g];

    f32x4 o_acc[4];
#pragma unroll
    for (int d = 0; d < 4; ++d) { o_acc[d][0]=0.f; o_acc[d][1]=0.f; o_acc[d][2]=0.f; o_acc[d][3]=0.f; }
    float m = -3e38f, l = 0.f;

    int skey = tid >> 3;
    int sd0  = (tid & 7) * 8;
    int kt_hi = (q0 + wave * 16 + 15) >> 5;
    int nkt = 2 * (qt + 1);

    for (int kt = 0; kt < nkt; ++kt) {
        __syncthreads();
        int s = kt * 32 + skey;
        bf16x8 kv = {0,0,0,0,0,0,0,0}, vv = {0,0,0,0,0,0,0,0};
        if (s < T_) {
            kv = *(const bf16x8*)&qkv[(rbase + s) * 1152 + qoff + 384 + sd0];
            vv = *(const bf16x8*)&qkv[(rbase + s) * 1152 + qoff + 768 + sd0];
        }
        *(bf16x8*)&K_lds[skey][sd0] = kv;
#pragma unroll
        for (int i = 0; i < 8; ++i) V_lds[sd0 + i][skey] = vv[i];
        __syncthreads();

        if (kt > kt_hi) continue;

        f32x4 s0, s1;
        s0[0]=0.f;s0[1]=0.f;s0[2]=0.f;s0[3]=0.f;
        s1[0]=0.f;s1[1]=0.f;s1[2]=0.f;s1[3]=0.f;
        {
            bf16x8 a00 = *(const bf16x8*)&K_lds[r16][8 * g];
            bf16x8 a01 = *(const bf16x8*)&K_lds[r16][32 + 8 * g];
            bf16x8 a10 = *(const bf16x8*)&K_lds[16 + r16][8 * g];
            bf16x8 a11 = *(const bf16x8*)&K_lds[16 + r16][32 + 8 * g];
            s0 = __builtin_amdgcn_mfma_f32_16x16x32_bf16(a00, qf0, s0, 0, 0, 0);
            s0 = __builtin_amdgcn_mfma_f32_16x16x32_bf16(a01, qf1, s0, 0, 0, 0);
            s1 = __builtin_amdgcn_mfma_f32_16x16x32_bf16(a10, qf0, s1, 0, 0, 0);
            s1 = __builtin_amdgcn_mfma_f32_16x16x32_bf16(a11, qf1, s1, 0, 0, 0);
        }

        int kb0 = kt * 32 + 4 * g;
        float sv[8];
#pragma unroll
        for (int r = 0; r < 4; ++r) {
            sv[r]     = (kb0 + r      <= qg) ? s0[r] * 0.125f : -3e38f;
            sv[4 + r] = (kb0 + 16 + r <= qg) ? s1[r] * 0.125f : -3e38f;
        }
        float pmax = sv[0];
#pragma unroll
        for (int i = 1; i < 8; ++i) pmax = fmaxf(pmax, sv[i]);
        pmax = fmaxf(pmax, __shfl_xor(pmax, 16, 64));
        pmax = fmaxf(pmax, __shfl_xor(pmax, 32, 64));
        float mn   = fmaxf(m, pmax);
        float corr = __expf(m - mn);
        float rs = 0.f;
        short pb[8];
#pragma unroll
        for (int i = 0; i < 8; ++i) {
            float p = __expf(sv[i] - mn);
            rs += p;
            pb[i] = f2bf(p);
        }
        rs += __shfl_xor(rs, 16, 64);
        rs += __shfl_xor(rs, 32, 64);
        l = l * corr + rs;
        m = mn;

        short4v t0, t1;
        t0[0]=pb[0]; t0[1]=pb[1]; t0[2]=pb[2]; t0[3]=pb[3];
        t1[0]=pb[4]; t1[1]=pb[5]; t1[2]=pb[6]; t1[3]=pb[7];
        *(short4v*)&P_lds[wave][r16][4 * g]      = t0;
        *(short4v*)&P_lds[wave][r16][16 + 4 * g] = t1;

#pragma unroll
        for (int d = 0; d < 4; ++d) {
            o_acc[d][0] *= corr; o_acc[d][1] *= corr;
            o_acc[d][2] *= corr; o_acc[d][3] *= corr;
        }
        bf16x8 pB = *(const bf16x8*)&P_lds[wave][r16][8 * g];
#pragma unroll
        for (int d = 0; d < 4; ++d) {
            bf16x8 vA = *(const bf16x8*)&V_lds[16 * d + r16][8 * g];
            o_acc[d] = __builtin_amdgcn_mfma_f32_16x16x32_bf16(vA, pB, o_acc[d], 0, 0, 0);
        }
    }

    float inv = (l > 0.f) ? 1.f / l : 0.f;
#pragma unroll
    for (int d = 0; d < 4; ++d)
#pragma unroll
        for (int r = 0; r < 4; ++r)
            O_lds[wave][r16][16 * d + 4 * g + r] = o_acc[d][r] * inv;
    for (int rr = 0; rr < 16; ++rr) {
        int tt = q0 + wave * 16 + rr;
        if (tt < T_) o[(rbase + tt) * C_ + qoff + lane] = f2bf(O_lds[wave][rr][lane]);
    }
}

// ---------------- per-row NLL ----------------
__global__ __launch_bounds__(64) void nll_kernel(const float* __restrict__ logits,
                                                 const int* __restrict__ tgt,
                                                 float* __restrict__ nll) {
    int row  = blockIdx.x;
    int lane = threadIdx.x;
    const float* rp = logits + (size_t)row * V_;
    float v[4];
    float mx = -INFINITY;
#pragma unroll
    for (int i = 0; i < 4; ++i) {
        v[i] = rp[i * 64 + lane];
        mx = fmaxf(mx, v[i]);
    }
#pragma unroll
    for (int o = 32; o > 0; o >>= 1) mx = fmaxf(mx, __shfl_xor(mx, o, 64));
    float s = 0.f;
#pragma unroll
    for (int i = 0; i < 4; ++i) s += expf(v[i] - mx);
#pragma unroll
    for (int o = 32; o > 0; o >>= 1) s += __shfl_xor(s, o, 64);
    if (lane == 0) {
        float lse = mx + logf(s);
        nll[row] = lse - rp[tgt[row]];
    }
}

// ---------------- final deterministic mean reduce ----------------
__global__ __launch_bounds__(256) void loss_kernel(const float* __restrict__ nll,
                                                   float* __restrict__ loss) {
    __shared__ float sm[256];
    float s = 0.f;
    for (int i = threadIdx.x; i < M_; i += 256) s += nll[i];
    sm[threadIdx.x] = s;
    __syncthreads();
    for (int o = 128; o > 0; o >>= 1) {
        if (threadIdx.x < o) sm[threadIdx.x] += sm[threadIdx.x + o];
        __syncthreads();
    }
    if (threadIdx.x == 0) *loss = sm[0] * (1.0f / M_);
}

// ---------------- host launcher ----------------
extern "C" void kernel_launch(void* const* d_in, const int* in_sizes, int n_in,
                              void* d_out, int out_size, void* d_ws, size_t ws_size,
                              hipStream_t stream) {
    const int*   x       = (const int*)d_in[0];
    const int*   targets = (const int*)d_in[1];
    const float* tok_emb = (const float*)d_in[2];
    const float* pos_emb = (const float*)d_in[3];
    const float* Wq      = (const float*)d_in[4];
    const float* Wk      = (const float*)d_in[5];
    const float* Wv      = (const float*)d_in[6];
    const float* Wo      = (const float*)d_in[7];
    const float* bo      = (const float*)d_in[8];
    const float* ln1_g   = (const float*)d_in[9];
    const float* ln1_b   = (const float*)d_in[10];
    const float* ln2_g   = (const float*)d_in[11];
    const float* ln2_b   = (const float*)d_in[12];
    const float* W1      = (const float*)d_in[13];
    const float* b1      = (const float*)d_in[14];
    const float* W2      = (const float*)d_in[15];
    const float* b2      = (const float*)d_in[16];
    const float* lnf_g   = (const float*)d_in[17];
    const float* lnf_b   = (const float*)d_in[18];
    const float* Wf      = (const float*)d_in[19];
    const float* bf      = (const float*)d_in[20];

    float* logits = (float*)d_out;
    float* loss   = logits + (size_t)M_ * V_;

    // workspace carve-up
    float* h    = (float*)d_ws;                          // [MP_][C_] fp32
    short* z    = (short*)(h + (size_t)MP_ * C_);        // [MP_][C_] bf16
    short* big  = z + (size_t)MP_ * C_;                  // [MP_][FF_] bf16 (qkv|ff shared)
    short* ob   = big + (size_t)MP_ * FF_;               // [MP_][C_] bf16
    short* qkvt = ob + (size_t)MP_ * C_;                 // [L][1152][384]
    short* wot  = qkvt + (size_t)L_ * 1152 * 384;        // [L][384][384]
    short* w1t  = wot + (size_t)L_ * 384 * 384;          // [L][1536][384]
    short* w2t  = w1t + (size_t)L_ * 1536 * 384;         // [L][384][1536]
    short* wft  = w2t + (size_t)L_ * 1536 * 384;         // [256][384]
    float* nll  = (float*)(wft + (size_t)256 * 384);     // [M_]

    wconv_kernel<<<10464, 256, 0, stream>>>(Wq, Wk, Wv, Wo, W1, W2, Wf,
                                            qkvt, wot, w1t, w2t, wft);
    embed_kernel<<<(M_ * C_ + 255) / 256, 256, 0, stream>>>(x, tok_emb, pos_emb, h);

    for (int l = 0; l < L_; ++l) {
        ln_kernel<<<M_, 64, 0, stream>>>(h, ln1_g + l * C_, ln1_b + l * C_, z);
        mm_kernel<0, false, false><<<dim3(128, 9), 256, 0, stream>>>(
            z, qkvt + (size_t)l * 1152 * 384, nullptr, big, nullptr, 1152, 384);
        attn_kernel<<<dim3(16, B_ * H_), 256, 0, stream>>>(big, ob);
        mm_kernel<1, false, true><<<dim3(128, 3), 256, 0, stream>>>(
            ob, wot + (size_t)l * 384 * 384, bo + l * C_, nullptr, h, 384, 384);
        ln_kernel<<<M_, 64, 0, stream>>>(h, ln2_g + l * C_, ln2_b + l * C_, z);
        mm_kernel<0, true, true><<<dim3(128, 12), 256, 0, stream>>>(
            z, w1t + (size_t)l * 1536 * 384, b1 + l * FF_, big, nullptr, 1536, 384);
        mm_kernel<1, false, true><<<dim3(128, 3), 256, 0, stream>>>(
            big, w2t + (size_t)l * 384 * 1536, b2 + l * C_, nullptr, h, 384, 1536);
    }

    ln_kernel<<<M_, 64, 0, stream>>>(h, lnf_g, lnf_b, z);
    mm_kernel<2, false, true><<<dim3(128, 2), 256, 0, stream>>>(
        z, wft, bf, nullptr, logits, 256, 384);

    nll_kernel<<<M_, 64, 0, stream>>>(logits, targets, nll);
    loss_kernel<<<1, 256, 0, stream>>>(nll, loss);
}

// Round 5
// 1689.436 us; speedup vs baseline: 19.8078x; 1.1080x over previous
//
#include <hip/hip_runtime.h>
#include <hip/hip_bf16.h>
#include <math.h>

// Problem constants
#define B_  16
#define T_  1023
#define C_  384
#define H_  6
#define DH_ 64
#define L_  6
#define V_  256
#define FF_ 1536
#define M_  (B_*T_)      // 16368 rows
#define MP_ 16384        // padded rows (128-multiple)
#define EPS_ 1e-5f

typedef __attribute__((ext_vector_type(8))) short bf16x8;
typedef __attribute__((ext_vector_type(4))) short short4v;
typedef __attribute__((ext_vector_type(4))) float f32x4;

__device__ inline short f2bf(float x) {   // RNE float->bf16
    union { float f; unsigned u; } c; c.f = x;
    unsigned r = (c.u + 0x7fffu + ((c.u >> 16) & 1u)) >> 16;
    return (short)r;
}

#define GLDS16(g, l) __builtin_amdgcn_global_load_lds(                         \
    (const __attribute__((address_space(1))) void*)(g),                        \
    (__attribute__((address_space(3))) void*)(l), 16, 0, 0)

// hardware transpose read: 4 bf16 per lane (rule #18: waitcnt+sched_barrier after)
#define TRRD(dst, va, IMM) asm volatile("ds_read_b64_tr_b16 %0, %1 offset:" IMM \
    : "=v"(dst) : "v"(va))

// ---------------- embedding: h = tok_emb[x] + pos_emb (fp32) ----------------
__global__ void embed_kernel(const int* __restrict__ x, const float* __restrict__ tok,
                             const float* __restrict__ pos, float* __restrict__ h) {
    int i = blockIdx.x * 256 + threadIdx.x;
    if (i >= M_ * C_) return;
    int bt = i / C_;
    int c  = i - bt * C_;
    int t  = bt % T_;
    h[i] = tok[x[bt] * C_ + c] + pos[t * C_ + c];
}

// ---------------- weight transpose+convert: src fp32 [K][N] -> dst bf16 [N][K] ----
__global__ __launch_bounds__(256) void wconv_kernel(
    const float* __restrict__ Wq, const float* __restrict__ Wk,
    const float* __restrict__ Wv, const float* __restrict__ Wo,
    const float* __restrict__ W1, const float* __restrict__ W2,
    const float* __restrict__ Wf,
    short* __restrict__ qkvt, short* __restrict__ wot, short* __restrict__ w1t,
    short* __restrict__ w2t, short* __restrict__ wft) {
    __shared__ float tile[32][33];
    int t = blockIdx.x;
    const float* src; short* dst; int K, N, tl;
    if (t < 10368) {
        int l = t / 1728, r = t - l * 1728;
        if (r < 432) {                 // Wq/Wk/Wv -> fused qkv^T rows
            int which = r / 144; tl = r - which * 144;
            src = (which == 0 ? Wq : which == 1 ? Wk : Wv) + (size_t)l * 384 * 384;
            dst = qkvt + (size_t)l * 1152 * 384 + (size_t)which * 384 * 384;
            K = 384; N = 384;
        } else if (r < 576) {
            tl = r - 432;
            src = Wo + (size_t)l * 384 * 384; dst = wot + (size_t)l * 384 * 384;
            K = 384; N = 384;
        } else if (r < 1152) {
            tl = r - 576;
            src = W1 + (size_t)l * 384 * 1536; dst = w1t + (size_t)l * 1536 * 384;
            K = 384; N = 1536;
        } else {
            tl = r - 1152;
            src = W2 + (size_t)l * 1536 * 384; dst = w2t + (size_t)l * 384 * 1536;
            K = 1536; N = 384;
        }
    } else {
        tl = t - 10368; src = Wf; dst = wft; K = 384; N = 256;
    }
    int ntx = N >> 5;
    int k0 = (tl / ntx) << 5, n0 = (tl % ntx) << 5;
    int rr = threadIdx.x >> 5, cc = threadIdx.x & 31;
#pragma unroll
    for (int p = 0; p < 4; ++p)
        tile[rr + 8 * p][cc] = src[(size_t)(k0 + rr + 8 * p) * N + n0 + cc];
    __syncthreads();
#pragma unroll
    for (int p = 0; p < 4; ++p)
        dst[(size_t)(n0 + rr + 8 * p) * K + k0 + cc] = f2bf(tile[cc][rr + 8 * p]);
}

// ---------------- LayerNorm: fp32 in -> bf16 out, one wave per row ----------------
__global__ __launch_bounds__(64) void ln_kernel(const float* __restrict__ in,
                                                const float* __restrict__ g,
                                                const float* __restrict__ b,
                                                short* __restrict__ out) {
    int row  = blockIdx.x;
    int lane = threadIdx.x;
    const float* rp = in + (size_t)row * C_;
    float v[6];
    float s = 0.f, s2 = 0.f;
#pragma unroll
    for (int i = 0; i < 6; ++i) {
        v[i] = rp[i * 64 + lane];
        s  += v[i];
        s2 += v[i] * v[i];
    }
#pragma unroll
    for (int o = 32; o > 0; o >>= 1) {
        s  += __shfl_xor(s,  o, 64);
        s2 += __shfl_xor(s2, o, 64);
    }
    float mu  = s * (1.0f / C_);
    float var = s2 * (1.0f / C_) - mu * mu;
    float rs  = rsqrtf(var + EPS_);
    short* op = out + (size_t)row * C_;
#pragma unroll
    for (int i = 0; i < 6; ++i) {
        int c = i * 64 + lane;
        op[c] = f2bf((v[i] - mu) * rs * g[c] + b[c]);
    }
}

// ---------------- bf16 MFMA GEMM: out = epilogue(A @ Bt^T) ----------------
template<int MODE, bool RELU, bool HB>
__global__ __launch_bounds__(256) void mm_kernel(const short* __restrict__ A,
                                                 const short* __restrict__ Bt,
                                                 const float* __restrict__ bias,
                                                 short* __restrict__ outb,
                                                 float* __restrict__ outf,
                                                 int N, int K) {
    __shared__ short Al[4][128][8];
    __shared__ short Bl[4][128][8];
    int tid  = threadIdx.x;
    int wave = tid >> 6, lane = tid & 63;
    int kg4 = lane >> 4, r16 = lane & 15;
    int wr = (wave >> 1) * 64, wc = (wave & 1) * 64;
    int row0 = blockIdx.x * 128, col0 = blockIdx.y * 128;

    const short* ga = A  + (size_t)(row0 + (tid & 127)) * K + ((tid >> 7) << 3);
    const short* gb = Bt + (size_t)(col0 + (tid & 127)) * K + ((tid >> 7) << 3);
    short* la = &Al[0][0][0] + tid * 8;
    short* lb = &Bl[0][0][0] + tid * 8;

    f32x4 acc[4][4];
#pragma unroll
    for (int i = 0; i < 4; ++i)
#pragma unroll
        for (int j = 0; j < 4; ++j) { acc[i][j][0]=0.f; acc[i][j][1]=0.f; acc[i][j][2]=0.f; acc[i][j][3]=0.f; }

    for (int k0 = 0; k0 < K; k0 += 32) {
        GLDS16(ga, la);          GLDS16(ga + 16, la + 2048);
        GLDS16(gb, lb);          GLDS16(gb + 16, lb + 2048);
        ga += 32; gb += 32;
        __syncthreads();

        bf16x8 av[4], bv[4];
#pragma unroll
        for (int i = 0; i < 4; ++i) av[i] = *(const bf16x8*)&Al[kg4][wr + 16 * i + r16][0];
#pragma unroll
        for (int j = 0; j < 4; ++j) bv[j] = *(const bf16x8*)&Bl[kg4][wc + 16 * j + r16][0];
#pragma unroll
        for (int i = 0; i < 4; ++i)
#pragma unroll
            for (int j = 0; j < 4; ++j)
                acc[i][j] = __builtin_amdgcn_mfma_f32_16x16x32_bf16(av[i], bv[j], acc[i][j], 0, 0, 0);
        __syncthreads();
    }

#pragma unroll
    for (int j = 0; j < 4; ++j) {
        int col = col0 + wc + 16 * j + r16;
        float bj = HB ? bias[col] : 0.f;
#pragma unroll
        for (int i = 0; i < 4; ++i) {
#pragma unroll
            for (int rg = 0; rg < 4; ++rg) {
                int row = row0 + wr + 16 * i + 4 * kg4 + rg;
                float v = acc[i][j][rg] + bj;
                if (RELU) v = fmaxf(v, 0.f);
                if (MODE == 0) {
                    outb[(size_t)row * N + col] = f2bf(v);
                } else if (MODE == 1) {
                    outf[(size_t)row * N + col] += v;
                } else {
                    if (row < M_) outf[(size_t)row * N + col] = v;
                }
            }
        }
    }
}

// ---------------- MFMA flash attention v2.1 ----------------
// qkv: [MP_][1152]; q at col hh*64, k at 384+hh*64, v at 768+hh*64 (bf16).
// 4 waves x 16 queries; 32-key tiles. K staged via global_load_lds into
// XOR-swizzled [key][oct^(key&7)] layout (source-swizzled, linear dest).
// V staged into [kq][dq][4][16] subtiles, read via ds_read_b64_tr_b16.
// FIX vs v2: tr_read address must be per-lane (base + 1024*g + 8*r16 bytes);
// v2 passed a group-uniform addr (m162: uniform addr => no transpose).
__global__ __launch_bounds__(256) void attn_kernel(const short* __restrict__ qkv,
                                                   short* __restrict__ o) {
    __shared__ short Kl[32 * 64];          // 4 KB
    __shared__ short Vl[32 * 64];          // 4 KB
    __shared__ short P_lds[4][16][40];     // 5 KB

    int tid  = threadIdx.x;
    int wave = tid >> 6;
    int lane = tid & 63;
    int g    = lane >> 4;
    int r16  = lane & 15;

    int qt = blockIdx.x;
    int bh = blockIdx.y;
    int b  = bh / H_, hh = bh - b * H_;
    size_t rbase = (size_t)b * T_;
    int qoff = hh * 64;

    int q0 = qt * 64;
    int qg = q0 + wave * 16 + r16;          // may be 1023 (pad query, never stored)

    const short* qrow = qkv + (rbase + qg) * 1152 + qoff;
    bf16x8 qf0 = *(const bf16x8*)(qrow + 8 * g);
    bf16x8 qf1 = *(const bf16x8*)(qrow + 32 + 8 * g);

    // staging sources (linear LDS dest = tid*16B; swizzle folded into source)
    int kkey = tid >> 3;
    int koct = (tid & 7) ^ (kkey & 7);
    const short* gk = qkv + (rbase + kkey) * 1152 + qoff + 384 + koct * 8;
    int vkey = 4 * (tid >> 5) + ((tid >> 1) & 3);
    int voct = 2 * ((tid >> 3) & 3) + (tid & 1);
    const short* gv = qkv + (rbase + vkey) * 1152 + qoff + 768 + voct * 8;
    short* lk = Kl + tid * 8;
    short* lv = Vl + tid * 8;

    f32x4 o_acc[4];
#pragma unroll
    for (int d = 0; d < 4; ++d) { o_acc[d][0]=0.f; o_acc[d][1]=0.f; o_acc[d][2]=0.f; o_acc[d][3]=0.f; }
    float m = -3e38f, l = 0.f;

    // per-lane read addresses
    const char* Kb = (const char*)Kl;
    unsigned ka = (unsigned)(r16 * 128 + ((g ^ (r16 & 7)) << 4));
    // V subtile (kq,dq) base byte = (kq*4+dq)*128; group g covers kq=2g,2g+1.
    // Lane slot term 8*r16 selects tile column r16 (m156 mapping).
    unsigned va = (unsigned)(size_t)(__attribute__((address_space(3))) short*)Vl
                + 1024u * (unsigned)g + 8u * (unsigned)r16;

    int kt_hi = (q0 + wave * 16 + 15) >> 5;
    int nkt = 2 * (qt + 1);

    for (int kt = 0; kt < nkt; ++kt) {
        __syncthreads();                       // prior tile's reads complete
        GLDS16(gk, lk);
        GLDS16(gv, lv);
        gk += 32 * 1152; gv += 32 * 1152;
        __syncthreads();                       // staging complete (vmcnt drained)

        if (kt <= kt_hi) {
            // ---- S^T = K @ Q^T ----
            f32x4 s0, s1;
            s0[0]=0.f;s0[1]=0.f;s0[2]=0.f;s0[3]=0.f;
            s1[0]=0.f;s1[1]=0.f;s1[2]=0.f;s1[3]=0.f;
            {
                bf16x8 a00 = *(const bf16x8*)(Kb + ka);
                bf16x8 a01 = *(const bf16x8*)(Kb + (ka ^ 64u));
                bf16x8 a10 = *(const bf16x8*)(Kb + ka + 2048u);
                bf16x8 a11 = *(const bf16x8*)(Kb + ((ka + 2048u) ^ 64u));
                s0 = __builtin_amdgcn_mfma_f32_16x16x32_bf16(a00, qf0, s0, 0, 0, 0);
                s0 = __builtin_amdgcn_mfma_f32_16x16x32_bf16(a01, qf1, s0, 0, 0, 0);
                s1 = __builtin_amdgcn_mfma_f32_16x16x32_bf16(a10, qf0, s1, 0, 0, 0);
                s1 = __builtin_amdgcn_mfma_f32_16x16x32_bf16(a11, qf1, s1, 0, 0, 0);
            }

            // ---- causal mask + online softmax ----
            int kb0 = kt * 32 + 4 * g;
            float sv[8];
#pragma unroll
            for (int r = 0; r < 4; ++r) {
                sv[r]     = (kb0 + r      <= qg) ? s0[r] * 0.125f : -3e38f;
                sv[4 + r] = (kb0 + 16 + r <= qg) ? s1[r] * 0.125f : -3e38f;
            }
            float pmax = sv[0];
#pragma unroll
            for (int i = 1; i < 8; ++i) pmax = fmaxf(pmax, sv[i]);
            pmax = fmaxf(pmax, __shfl_xor(pmax, 16, 64));
            pmax = fmaxf(pmax, __shfl_xor(pmax, 32, 64));
            float mn   = fmaxf(m, pmax);
            float corr = __expf(m - mn);
            float rs = 0.f;
            short pb[8];
#pragma unroll
            for (int i = 0; i < 8; ++i) {
                float p = __expf(sv[i] - mn);
                rs += p;
                pb[i] = f2bf(p);
            }
            rs += __shfl_xor(rs, 16, 64);
            rs += __shfl_xor(rs, 32, 64);
            l = l * corr + rs;
            m = mn;

            short4v t0w, t1w;
            t0w[0]=pb[0]; t0w[1]=pb[1]; t0w[2]=pb[2]; t0w[3]=pb[3];
            t1w[0]=pb[4]; t1w[1]=pb[5]; t1w[2]=pb[6]; t1w[3]=pb[7];
            *(short4v*)&P_lds[wave][r16][4 * g]      = t0w;
            *(short4v*)&P_lds[wave][r16][16 + 4 * g] = t1w;

            // ---- PV: issue transpose reads of V, scale O, then MFMA ----
            short4v v0, v1, v2, v3, v4, v5, v6, v7;
            TRRD(v0, va, "0");    TRRD(v1, va, "512");
            TRRD(v2, va, "128");  TRRD(v3, va, "640");
            TRRD(v4, va, "256");  TRRD(v5, va, "768");
            TRRD(v6, va, "384");  TRRD(v7, va, "896");

            bf16x8 pB = *(const bf16x8*)&P_lds[wave][r16][8 * g];
#pragma unroll
            for (int d = 0; d < 4; ++d) {
                o_acc[d][0] *= corr; o_acc[d][1] *= corr;
                o_acc[d][2] *= corr; o_acc[d][3] *= corr;
            }
            asm volatile("s_waitcnt lgkmcnt(0)" ::: "memory");
            __builtin_amdgcn_sched_barrier(0);

            bf16x8 av0, av1, av2, av3;
#pragma unroll
            for (int i = 0; i < 4; ++i) {
                av0[i] = v0[i]; av0[i + 4] = v1[i];
                av1[i] = v2[i]; av1[i + 4] = v3[i];
                av2[i] = v4[i]; av2[i + 4] = v5[i];
                av3[i] = v6[i]; av3[i + 4] = v7[i];
            }
            o_acc[0] = __builtin_amdgcn_mfma_f32_16x16x32_bf16(av0, pB, o_acc[0], 0, 0, 0);
            o_acc[1] = __builtin_amdgcn_mfma_f32_16x16x32_bf16(av1, pB, o_acc[1], 0, 0, 0);
            o_acc[2] = __builtin_amdgcn_mfma_f32_16x16x32_bf16(av2, pB, o_acc[2], 0, 0, 0);
            o_acc[3] = __builtin_amdgcn_mfma_f32_16x16x32_bf16(av3, pB, o_acc[3], 0, 0, 0);
        }
    }

    // ---- epilogue: direct bf16 writes (lane owns query qg, d = 16d+4g+r) ----
    float inv = (l > 0.f) ? 1.f / l : 0.f;
    if (qg < T_) {
        short* orow = o + (rbase + qg) * C_ + qoff;
#pragma unroll
        for (int d = 0; d < 4; ++d) {
            short4v ov;
#pragma unroll
            for (int r = 0; r < 4; ++r) ov[r] = f2bf(o_acc[d][r] * inv);
            *(short4v*)(orow + 16 * d + 4 * g) = ov;
        }
    }
}

// ---------------- per-row NLL ----------------
__global__ __launch_bounds__(64) void nll_kernel(const float* __restrict__ logits,
                                                 const int* __restrict__ tgt,
                                                 float* __restrict__ nll) {
    int row  = blockIdx.x;
    int lane = threadIdx.x;
    const float* rp = logits + (size_t)row * V_;
    float v[4];
    float mx = -INFINITY;
#pragma unroll
    for (int i = 0; i < 4; ++i) {
        v[i] = rp[i * 64 + lane];
        mx = fmaxf(mx, v[i]);
    }
#pragma unroll
    for (int o = 32; o > 0; o >>= 1) mx = fmaxf(mx, __shfl_xor(mx, o, 64));
    float s = 0.f;
#pragma unroll
    for (int i = 0; i < 4; ++i) s += expf(v[i] - mx);
#pragma unroll
    for (int o = 32; o > 0; o >>= 1) s += __shfl_xor(s, o, 64);
    if (lane == 0) {
        float lse = mx + logf(s);
        nll[row] = lse - rp[tgt[row]];
    }
}

// ---------------- final deterministic mean reduce ----------------
__global__ __launch_bounds__(256) void loss_kernel(const float* __restrict__ nll,
                                                   float* __restrict__ loss) {
    __shared__ float sm[256];
    float s = 0.f;
    for (int i = threadIdx.x; i < M_; i += 256) s += nll[i];
    sm[threadIdx.x] = s;
    __syncthreads();
    for (int o = 128; o > 0; o >>= 1) {
        if (threadIdx.x < o) sm[threadIdx.x] += sm[threadIdx.x + o];
        __syncthreads();
    }
    if (threadIdx.x == 0) *loss = sm[0] * (1.0f / M_);
}

// ---------------- host launcher ----------------
extern "C" void kernel_launch(void* const* d_in, const int* in_sizes, int n_in,
                              void* d_out, int out_size, void* d_ws, size_t ws_size,
                              hipStream_t stream) {
    const int*   x       = (const int*)d_in[0];
    const int*   targets = (const int*)d_in[1];
    const float* tok_emb = (const float*)d_in[2];
    const float* pos_emb = (const float*)d_in[3];
    const float* Wq      = (const float*)d_in[4];
    const float* Wk      = (const float*)d_in[5];
    const float* Wv      = (const float*)d_in[6];
    const float* Wo      = (const float*)d_in[7];
    const float* bo      = (const float*)d_in[8];
    const float* ln1_g   = (const float*)d_in[9];
    const float* ln1_b   = (const float*)d_in[10];
    const float* ln2_g   = (const float*)d_in[11];
    const float* ln2_b   = (const float*)d_in[12];
    const float* W1      = (const float*)d_in[13];
    const float* b1      = (const float*)d_in[14];
    const float* W2      = (const float*)d_in[15];
    const float* b2      = (const float*)d_in[16];
    const float* lnf_g   = (const float*)d_in[17];
    const float* lnf_b   = (const float*)d_in[18];
    const float* Wf      = (const float*)d_in[19];
    const float* bf      = (const float*)d_in[20];

    float* logits = (float*)d_out;
    float* loss   = logits + (size_t)M_ * V_;

    float* h    = (float*)d_ws;                          // [MP_][C_] fp32
    short* z    = (short*)(h + (size_t)MP_ * C_);        // [MP_][C_] bf16
    short* big  = z + (size_t)MP_ * C_;                  // [MP_][FF_] bf16 (qkv|ff)
    short* ob   = big + (size_t)MP_ * FF_;               // [MP_][C_] bf16
    short* qkvt = ob + (size_t)MP_ * C_;                 // [L][1152][384]
    short* wot  = qkvt + (size_t)L_ * 1152 * 384;        // [L][384][384]
    short* w1t  = wot + (size_t)L_ * 384 * 384;          // [L][1536][384]
    short* w2t  = w1t + (size_t)L_ * 1536 * 384;         // [L][384][1536]
    short* wft  = w2t + (size_t)L_ * 1536 * 384;         // [256][384]
    float* nll  = (float*)(wft + (size_t)256 * 384);     // [M_]

    wconv_kernel<<<10464, 256, 0, stream>>>(Wq, Wk, Wv, Wo, W1, W2, Wf,
                                            qkvt, wot, w1t, w2t, wft);
    embed_kernel<<<(M_ * C_ + 255) / 256, 256, 0, stream>>>(x, tok_emb, pos_emb, h);

    for (int l = 0; l < L_; ++l) {
        ln_kernel<<<M_, 64, 0, stream>>>(h, ln1_g + l * C_, ln1_b + l * C_, z);
        mm_kernel<0, false, false><<<dim3(128, 9), 256, 0, stream>>>(
            z, qkvt + (size_t)l * 1152 * 384, nullptr, big, nullptr, 1152, 384);
        attn_kernel<<<dim3(16, B_ * H_), 256, 0, stream>>>(big, ob);
        mm_kernel<1, false, true><<<dim3(128, 3), 256, 0, stream>>>(
            ob, wot + (size_t)l * 384 * 384, bo + l * C_, nullptr, h, 384, 384);
        ln_kernel<<<M_, 64, 0, stream>>>(h, ln2_g + l * C_, ln2_b + l * C_, z);
        mm_kernel<0, true, true><<<dim3(128, 12), 256, 0, stream>>>(
            z, w1t + (size_t)l * 1536 * 384, b1 + l * FF_, big, nullptr, 1536, 384);
        mm_kernel<1, false, true><<<dim3(128, 3), 256, 0, stream>>>(
            big, w2t + (size_t)l * 384 * 1536, b2 + l * C_, nullptr, h, 384, 1536);
    }

    ln_kernel<<<M_, 64, 0, stream>>>(h, lnf_g, lnf_b, z);
    mm_kernel<2, false, true><<<dim3(128, 2), 256, 0, stream>>>(
        z, wft, bf, nullptr, logits, 256, 384);

    nll_kernel<<<M_, 64, 0, stream>>>(logits, targets, nll);
    loss_kernel<<<1, 256, 0, stream>>>(nll, loss);
}

// Round 6
// 1545.047 us; speedup vs baseline: 21.6589x; 1.0935x over previous
//
#include <hip/hip_runtime.h>
#include <hip/hip_bf16.h>
#include <math.h>

// Problem constants
#define B_  16
#define T_  1023
#define C_  384
#define H_  6
#define DH_ 64
#define L_  6
#define V_  256
#define FF_ 1536
#define M_  (B_*T_)      // 16368 rows
#define MP_ 16384        // padded rows (128-multiple)
#define EPS_ 1e-5f

typedef __attribute__((ext_vector_type(8))) short bf16x8;
typedef __attribute__((ext_vector_type(4))) short short4v;
typedef __attribute__((ext_vector_type(4))) float f32x4;

__device__ inline short f2bf(float x) {   // RNE float->bf16
    union { float f; unsigned u; } c; c.f = x;
    unsigned r = (c.u + 0x7fffu + ((c.u >> 16) & 1u)) >> 16;
    return (short)r;
}

#define GLDS16(g, l) __builtin_amdgcn_global_load_lds(                         \
    (const __attribute__((address_space(1))) void*)(g),                        \
    (__attribute__((address_space(3))) void*)(l), 16, 0, 0)

// hardware transpose read: 4 bf16 per lane (rule #18: waitcnt+sched_barrier after)
#define TRRD(dst, va, IMM) asm volatile("ds_read_b64_tr_b16 %0, %1 offset:" IMM \
    : "=v"(dst) : "v"(va))

// ---------------- embedding: h = tok_emb[x] + pos_emb (fp32) ----------------
__global__ void embed_kernel(const int* __restrict__ x, const float* __restrict__ tok,
                             const float* __restrict__ pos, float* __restrict__ h) {
    int i = blockIdx.x * 256 + threadIdx.x;
    if (i >= M_ * C_) return;
    int bt = i / C_;
    int c  = i - bt * C_;
    int t  = bt % T_;
    h[i] = tok[x[bt] * C_ + c] + pos[t * C_ + c];
}

// ---------------- weight transpose+convert: src fp32 [K][N] -> dst bf16 [N][K] ----
__global__ __launch_bounds__(256) void wconv_kernel(
    const float* __restrict__ Wq, const float* __restrict__ Wk,
    const float* __restrict__ Wv, const float* __restrict__ Wo,
    const float* __restrict__ W1, const float* __restrict__ W2,
    const float* __restrict__ Wf,
    short* __restrict__ qkvt, short* __restrict__ wot, short* __restrict__ w1t,
    short* __restrict__ w2t, short* __restrict__ wft) {
    __shared__ float tile[32][33];
    int t = blockIdx.x;
    const float* src; short* dst; int K, N, tl;
    if (t < 10368) {
        int l = t / 1728, r = t - l * 1728;
        if (r < 432) {                 // Wq/Wk/Wv -> fused qkv^T rows
            int which = r / 144; tl = r - which * 144;
            src = (which == 0 ? Wq : which == 1 ? Wk : Wv) + (size_t)l * 384 * 384;
            dst = qkvt + (size_t)l * 1152 * 384 + (size_t)which * 384 * 384;
            K = 384; N = 384;
        } else if (r < 576) {
            tl = r - 432;
            src = Wo + (size_t)l * 384 * 384; dst = wot + (size_t)l * 384 * 384;
            K = 384; N = 384;
        } else if (r < 1152) {
            tl = r - 576;
            src = W1 + (size_t)l * 384 * 1536; dst = w1t + (size_t)l * 1536 * 384;
            K = 384; N = 1536;
        } else {
            tl = r - 1152;
            src = W2 + (size_t)l * 1536 * 384; dst = w2t + (size_t)l * 384 * 1536;
            K = 1536; N = 384;
        }
    } else {
        tl = t - 10368; src = Wf; dst = wft; K = 384; N = 256;
    }
    int ntx = N >> 5;
    int k0 = (tl / ntx) << 5, n0 = (tl % ntx) << 5;
    int rr = threadIdx.x >> 5, cc = threadIdx.x & 31;
#pragma unroll
    for (int p = 0; p < 4; ++p)
        tile[rr + 8 * p][cc] = src[(size_t)(k0 + rr + 8 * p) * N + n0 + cc];
    __syncthreads();
#pragma unroll
    for (int p = 0; p < 4; ++p)
        dst[(size_t)(n0 + rr + 8 * p) * K + k0 + cc] = f2bf(tile[cc][rr + 8 * p]);
}

// ---------------- LayerNorm: fp32 in -> bf16 out, 4 rows per block ----------------
__global__ __launch_bounds__(256) void ln_kernel(const float* __restrict__ in,
                                                 const float* __restrict__ g,
                                                 const float* __restrict__ b,
                                                 short* __restrict__ out) {
    int wave = threadIdx.x >> 6, lane = threadIdx.x & 63;
    int row  = blockIdx.x * 4 + wave;       // M_ = 4092*4 exactly
    const float* rp = in + (size_t)row * C_;
    float v[6];
    float s = 0.f, s2 = 0.f;
#pragma unroll
    for (int i = 0; i < 6; ++i) {
        v[i] = rp[i * 64 + lane];
        s  += v[i];
        s2 += v[i] * v[i];
    }
#pragma unroll
    for (int o = 32; o > 0; o >>= 1) {
        s  += __shfl_xor(s,  o, 64);
        s2 += __shfl_xor(s2, o, 64);
    }
    float mu  = s * (1.0f / C_);
    float var = s2 * (1.0f / C_) - mu * mu;
    float rs  = rsqrtf(var + EPS_);
    short* op = out + (size_t)row * C_;
#pragma unroll
    for (int i = 0; i < 6; ++i) {
        int c = i * 64 + lane;
        op[c] = f2bf((v[i] - mu) * rs * g[c] + b[c]);
    }
}

// ---------------- bf16 MFMA GEMM: 2-phase double-buffered pipeline ----------------
// A: bf16 [MP_][K]; Bt: bf16 [N][K]. 128x128 tile, BK=32, 4 waves.
// T3-minimum: stage(next) issued BEFORE compute(cur); vmcnt(0)+raw barrier per tile.
template<int MODE, bool RELU, bool HB>
__global__ __launch_bounds__(256) void mm_kernel(const short* __restrict__ A,
                                                 const short* __restrict__ Bt,
                                                 const float* __restrict__ bias,
                                                 short* __restrict__ outb,
                                                 float* __restrict__ outf,
                                                 int N, int K) {
    __shared__ short Al[2][4][128][8];   // [dbuf][k-octet][row][8]
    __shared__ short Bl[2][4][128][8];
    int tid  = threadIdx.x;
    int wave = tid >> 6, lane = tid & 63;
    int kg4 = lane >> 4, r16 = lane & 15;
    int wr = (wave >> 1) * 64, wc = (wave & 1) * 64;
    int row0 = blockIdx.x * 128, col0 = blockIdx.y * 128;

    const short* ga = A  + (size_t)(row0 + (tid & 127)) * K + ((tid >> 7) << 3);
    const short* gb = Bt + (size_t)(col0 + (tid & 127)) * K + ((tid >> 7) << 3);
    short* alds = &Al[0][0][0][0];
    short* blds = &Bl[0][0][0][0];

    f32x4 acc[4][4];
#pragma unroll
    for (int i = 0; i < 4; ++i)
#pragma unroll
        for (int j = 0; j < 4; ++j) { acc[i][j][0]=0.f; acc[i][j][1]=0.f; acc[i][j][2]=0.f; acc[i][j][3]=0.f; }

#define MM_STAGE(BUF)                                                          \
    {                                                                          \
        short* la = alds + (BUF) * 4096 + tid * 8;                             \
        short* lb = blds + (BUF) * 4096 + tid * 8;                             \
        GLDS16(ga, la); GLDS16(ga + 16, la + 2048);                            \
        GLDS16(gb, lb); GLDS16(gb + 16, lb + 2048);                            \
    }

#define MM_COMPUTE(BUF)                                                        \
    {                                                                          \
        const short* ab = alds + (BUF) * 4096 + kg4 * 1024;                    \
        const short* bb = blds + (BUF) * 4096 + kg4 * 1024;                    \
        bf16x8 av[4], bv[4];                                                   \
        _Pragma("unroll")                                                      \
        for (int i = 0; i < 4; ++i) av[i] = *(const bf16x8*)(ab + (wr + 16*i + r16) * 8); \
        _Pragma("unroll")                                                      \
        for (int j = 0; j < 4; ++j) bv[j] = *(const bf16x8*)(bb + (wc + 16*j + r16) * 8); \
        _Pragma("unroll")                                                      \
        for (int i = 0; i < 4; ++i)                                            \
            _Pragma("unroll")                                                  \
            for (int j = 0; j < 4; ++j)                                        \
                acc[i][j] = __builtin_amdgcn_mfma_f32_16x16x32_bf16(av[i], bv[j], acc[i][j], 0, 0, 0); \
    }

    int NT = K >> 5;
    MM_STAGE(0);
    asm volatile("s_waitcnt vmcnt(0)" ::: "memory");
    __builtin_amdgcn_s_barrier();
    asm volatile("" ::: "memory");

    int cur = 0;
    for (int t = 0; t < NT - 1; ++t) {
        ga += 32; gb += 32;
        MM_STAGE(cur ^ 1);
        MM_COMPUTE(cur);
        asm volatile("s_waitcnt vmcnt(0)" ::: "memory");
        __builtin_amdgcn_s_barrier();
        asm volatile("" ::: "memory");
        cur ^= 1;
    }
    MM_COMPUTE(cur);
#undef MM_STAGE
#undef MM_COMPUTE

#pragma unroll
    for (int j = 0; j < 4; ++j) {
        int col = col0 + wc + 16 * j + r16;
        float bj = HB ? bias[col] : 0.f;
#pragma unroll
        for (int i = 0; i < 4; ++i) {
#pragma unroll
            for (int rg = 0; rg < 4; ++rg) {
                int row = row0 + wr + 16 * i + 4 * kg4 + rg;
                float v = acc[i][j][rg] + bj;
                if (RELU) v = fmaxf(v, 0.f);
                if (MODE == 0) {
                    outb[(size_t)row * N + col] = f2bf(v);
                } else if (MODE == 1) {
                    outf[(size_t)row * N + col] += v;
                } else {
                    if (row < M_) outf[(size_t)row * N + col] = v;
                }
            }
        }
    }
}

// ---------------- MFMA flash attention v3: paired q-tiles ----------------
// Block handles q-tiles (a, 15-a); one staged K/V tile feeds both accumulators.
// Every block does exactly 34 tile-units of MFMA -> uniform duration.
__device__ __forceinline__ void attn_step(int kt, int qg, int g, int r16,
                                          const char* Kb, unsigned ka, unsigned va,
                                          short (*Pw)[40],
                                          bf16x8 qf0, bf16x8 qf1,
                                          f32x4* o_acc, float& m, float& l) {
    // ---- S^T = K @ Q^T ----
    f32x4 s0, s1;
    s0[0]=0.f;s0[1]=0.f;s0[2]=0.f;s0[3]=0.f;
    s1[0]=0.f;s1[1]=0.f;s1[2]=0.f;s1[3]=0.f;
    bf16x8 a00 = *(const bf16x8*)(Kb + ka);
    bf16x8 a01 = *(const bf16x8*)(Kb + (ka ^ 64u));
    bf16x8 a10 = *(const bf16x8*)(Kb + ka + 2048u);
    bf16x8 a11 = *(const bf16x8*)(Kb + ((ka + 2048u) ^ 64u));
    s0 = __builtin_amdgcn_mfma_f32_16x16x32_bf16(a00, qf0, s0, 0, 0, 0);
    s0 = __builtin_amdgcn_mfma_f32_16x16x32_bf16(a01, qf1, s0, 0, 0, 0);
    s1 = __builtin_amdgcn_mfma_f32_16x16x32_bf16(a10, qf0, s1, 0, 0, 0);
    s1 = __builtin_amdgcn_mfma_f32_16x16x32_bf16(a11, qf1, s1, 0, 0, 0);

    // ---- causal mask + online softmax ----
    int kb0 = kt * 32 + 4 * g;
    float sv[8];
#pragma unroll
    for (int r = 0; r < 4; ++r) {
        sv[r]     = (kb0 + r      <= qg) ? s0[r] * 0.125f : -3e38f;
        sv[4 + r] = (kb0 + 16 + r <= qg) ? s1[r] * 0.125f : -3e38f;
    }
    float pmax = sv[0];
#pragma unroll
    for (int i = 1; i < 8; ++i) pmax = fmaxf(pmax, sv[i]);
    pmax = fmaxf(pmax, __shfl_xor(pmax, 16, 64));
    pmax = fmaxf(pmax, __shfl_xor(pmax, 32, 64));
    float mn   = fmaxf(m, pmax);
    float corr = __expf(m - mn);
    float rs = 0.f;
    short pb[8];
#pragma unroll
    for (int i = 0; i < 8; ++i) {
        float p = __expf(sv[i] - mn);
        rs += p;
        pb[i] = f2bf(p);
    }
    rs += __shfl_xor(rs, 16, 64);
    rs += __shfl_xor(rs, 32, 64);
    l = l * corr + rs;
    m = mn;

    short4v t0w, t1w;
    t0w[0]=pb[0]; t0w[1]=pb[1]; t0w[2]=pb[2]; t0w[3]=pb[3];
    t1w[0]=pb[4]; t1w[1]=pb[5]; t1w[2]=pb[6]; t1w[3]=pb[7];
    *(short4v*)&Pw[r16][4 * g]      = t0w;
    *(short4v*)&Pw[r16][16 + 4 * g] = t1w;

    // ---- PV: transpose reads of V, scale O, MFMA ----
    short4v v0, v1, v2, v3, v4, v5, v6, v7;
    TRRD(v0, va, "0");    TRRD(v1, va, "512");
    TRRD(v2, va, "128");  TRRD(v3, va, "640");
    TRRD(v4, va, "256");  TRRD(v5, va, "768");
    TRRD(v6, va, "384");  TRRD(v7, va, "896");

    bf16x8 pB = *(const bf16x8*)&Pw[r16][8 * g];
#pragma unroll
    for (int d = 0; d < 4; ++d) {
        o_acc[d][0] *= corr; o_acc[d][1] *= corr;
        o_acc[d][2] *= corr; o_acc[d][3] *= corr;
    }
    asm volatile("s_waitcnt lgkmcnt(0)" ::: "memory");
    __builtin_amdgcn_sched_barrier(0);

    bf16x8 av0, av1, av2, av3;
#pragma unroll
    for (int i = 0; i < 4; ++i) {
        av0[i] = v0[i]; av0[i + 4] = v1[i];
        av1[i] = v2[i]; av1[i + 4] = v3[i];
        av2[i] = v4[i]; av2[i + 4] = v5[i];
        av3[i] = v6[i]; av3[i + 4] = v7[i];
    }
    o_acc[0] = __builtin_amdgcn_mfma_f32_16x16x32_bf16(av0, pB, o_acc[0], 0, 0, 0);
    o_acc[1] = __builtin_amdgcn_mfma_f32_16x16x32_bf16(av1, pB, o_acc[1], 0, 0, 0);
    o_acc[2] = __builtin_amdgcn_mfma_f32_16x16x32_bf16(av2, pB, o_acc[2], 0, 0, 0);
    o_acc[3] = __builtin_amdgcn_mfma_f32_16x16x32_bf16(av3, pB, o_acc[3], 0, 0, 0);
}

__global__ __launch_bounds__(256) void attn_kernel(const short* __restrict__ qkv,
                                                   short* __restrict__ o) {
    __shared__ short Kl[32 * 64];          // 4 KB
    __shared__ short Vl[32 * 64];          // 4 KB
    __shared__ short P_lds[4][16][40];     // 5 KB

    int tid  = threadIdx.x;
    int wave = tid >> 6;
    int lane = tid & 63;
    int g    = lane >> 4;
    int r16  = lane & 15;

    int qtA = blockIdx.x;          // 0..7
    int qtB = 15 - qtA;            // 15..8
    int bh = blockIdx.y;
    int b  = bh / H_, hh = bh - b * H_;
    size_t rbase = (size_t)b * T_;
    int qoff = hh * 64;

    int q0A = qtA * 64, q0B = qtB * 64;
    int qgA = q0A + wave * 16 + r16;
    int qgB = q0B + wave * 16 + r16;       // may be 1023 (pad query, never stored)

    const short* qrA = qkv + (rbase + qgA) * 1152 + qoff;
    const short* qrB = qkv + (rbase + qgB) * 1152 + qoff;
    bf16x8 qfA0 = *(const bf16x8*)(qrA + 8 * g);
    bf16x8 qfA1 = *(const bf16x8*)(qrA + 32 + 8 * g);
    bf16x8 qfB0 = *(const bf16x8*)(qrB + 8 * g);
    bf16x8 qfB1 = *(const bf16x8*)(qrB + 32 + 8 * g);

    // staging sources (linear LDS dest = tid*16B; swizzle folded into source)
    int kkey = tid >> 3;
    int koct = (tid & 7) ^ (kkey & 7);
    const short* gk = qkv + (rbase + kkey) * 1152 + qoff + 384 + koct * 8;
    int vkey = 4 * (tid >> 5) + ((tid >> 1) & 3);
    int voct = 2 * ((tid >> 3) & 3) + (tid & 1);
    const short* gv = qkv + (rbase + vkey) * 1152 + qoff + 768 + voct * 8;
    short* lk = Kl + tid * 8;
    short* lv = Vl + tid * 8;

    f32x4 oA[4], oB[4];
#pragma unroll
    for (int d = 0; d < 4; ++d) {
        oA[d][0]=0.f; oA[d][1]=0.f; oA[d][2]=0.f; oA[d][3]=0.f;
        oB[d][0]=0.f; oB[d][1]=0.f; oB[d][2]=0.f; oB[d][3]=0.f;
    }
    float mA = -3e38f, lA = 0.f, mB = -3e38f, lB = 0.f;

    const char* Kb = (const char*)Kl;
    unsigned ka = (unsigned)(r16 * 128 + ((g ^ (r16 & 7)) << 4));
    unsigned va = (unsigned)(size_t)(__attribute__((address_space(3))) short*)Vl
                + 1024u * (unsigned)g + 8u * (unsigned)r16;

    int ktA_hi = (q0A + wave * 16 + 15) >> 5;
    int ktB_hi = (q0B + wave * 16 + 15) >> 5;
    int nkt = 2 * (qtB + 1);

    for (int kt = 0; kt < nkt; ++kt) {
        __syncthreads();                       // prior tile's reads complete
        GLDS16(gk, lk);
        GLDS16(gv, lv);
        gk += 32 * 1152; gv += 32 * 1152;
        __syncthreads();                       // staging complete (vmcnt drained)

        if (kt <= ktB_hi)
            attn_step(kt, qgB, g, r16, Kb, ka, va, P_lds[wave], qfB0, qfB1, oB, mB, lB);
        if (kt <= ktA_hi)
            attn_step(kt, qgA, g, r16, Kb, ka, va, P_lds[wave], qfA0, qfA1, oA, mA, lA);
    }

    // ---- epilogue: direct bf16 writes (lane owns its query; d = 16d+4g+r) ----
    {
        float inv = (lA > 0.f) ? 1.f / lA : 0.f;
        short* orow = o + (rbase + qgA) * C_ + qoff;
#pragma unroll
        for (int d = 0; d < 4; ++d) {
            short4v ov;
#pragma unroll
            for (int r = 0; r < 4; ++r) ov[r] = f2bf(oA[d][r] * inv);
            *(short4v*)(orow + 16 * d + 4 * g) = ov;
        }
    }
    if (qgB < T_) {
        float inv = (lB > 0.f) ? 1.f / lB : 0.f;
        short* orow = o + (rbase + qgB) * C_ + qoff;
#pragma unroll
        for (int d = 0; d < 4; ++d) {
            short4v ov;
#pragma unroll
            for (int r = 0; r < 4; ++r) ov[r] = f2bf(oB[d][r] * inv);
            *(short4v*)(orow + 16 * d + 4 * g) = ov;
        }
    }
}

// ---------------- per-row NLL ----------------
__global__ __launch_bounds__(64) void nll_kernel(const float* __restrict__ logits,
                                                 const int* __restrict__ tgt,
                                                 float* __restrict__ nll) {
    int row  = blockIdx.x;
    int lane = threadIdx.x;
    const float* rp = logits + (size_t)row * V_;
    float v[4];
    float mx = -INFINITY;
#pragma unroll
    for (int i = 0; i < 4; ++i) {
        v[i] = rp[i * 64 + lane];
        mx = fmaxf(mx, v[i]);
    }
#pragma unroll
    for (int o = 32; o > 0; o >>= 1) mx = fmaxf(mx, __shfl_xor(mx, o, 64));
    float s = 0.f;
#pragma unroll
    for (int i = 0; i < 4; ++i) s += expf(v[i] - mx);
#pragma unroll
    for (int o = 32; o > 0; o >>= 1) s += __shfl_xor(s, o, 64);
    if (lane == 0) {
        float lse = mx + logf(s);
        nll[row] = lse - rp[tgt[row]];
    }
}

// ---------------- final deterministic mean reduce ----------------
__global__ __launch_bounds__(256) void loss_kernel(const float* __restrict__ nll,
                                                   float* __restrict__ loss) {
    __shared__ float sm[256];
    float s = 0.f;
    for (int i = threadIdx.x; i < M_; i += 256) s += nll[i];
    sm[threadIdx.x] = s;
    __syncthreads();
    for (int o = 128; o > 0; o >>= 1) {
        if (threadIdx.x < o) sm[threadIdx.x] += sm[threadIdx.x + o];
        __syncthreads();
    }
    if (threadIdx.x == 0) *loss = sm[0] * (1.0f / M_);
}

// ---------------- host launcher ----------------
extern "C" void kernel_launch(void* const* d_in, const int* in_sizes, int n_in,
                              void* d_out, int out_size, void* d_ws, size_t ws_size,
                              hipStream_t stream) {
    const int*   x       = (const int*)d_in[0];
    const int*   targets = (const int*)d_in[1];
    const float* tok_emb = (const float*)d_in[2];
    const float* pos_emb = (const float*)d_in[3];
    const float* Wq      = (const float*)d_in[4];
    const float* Wk      = (const float*)d_in[5];
    const float* Wv      = (const float*)d_in[6];
    const float* Wo      = (const float*)d_in[7];
    const float* bo      = (const float*)d_in[8];
    const float* ln1_g   = (const float*)d_in[9];
    const float* ln1_b   = (const float*)d_in[10];
    const float* ln2_g   = (const float*)d_in[11];
    const float* ln2_b   = (const float*)d_in[12];
    const float* W1      = (const float*)d_in[13];
    const float* b1      = (const float*)d_in[14];
    const float* W2      = (const float*)d_in[15];
    const float* b2      = (const float*)d_in[16];
    const float* lnf_g   = (const float*)d_in[17];
    const float* lnf_b   = (const float*)d_in[18];
    const float* Wf      = (const float*)d_in[19];
    const float* bf      = (const float*)d_in[20];

    float* logits = (float*)d_out;
    float* loss   = logits + (size_t)M_ * V_;

    float* h    = (float*)d_ws;                          // [MP_][C_] fp32
    short* z    = (short*)(h + (size_t)MP_ * C_);        // [MP_][C_] bf16
    short* big  = z + (size_t)MP_ * C_;                  // [MP_][FF_] bf16 (qkv|ff)
    short* ob   = big + (size_t)MP_ * FF_;               // [MP_][C_] bf16
    short* qkvt = ob + (size_t)MP_ * C_;                 // [L][1152][384]
    short* wot  = qkvt + (size_t)L_ * 1152 * 384;        // [L][384][384]
    short* w1t  = wot + (size_t)L_ * 384 * 384;          // [L][1536][384]
    short* w2t  = w1t + (size_t)L_ * 1536 * 384;         // [L][384][1536]
    short* wft  = w2t + (size_t)L_ * 1536 * 384;         // [256][384]
    float* nll  = (float*)(wft + (size_t)256 * 384);     // [M_]

    wconv_kernel<<<10464, 256, 0, stream>>>(Wq, Wk, Wv, Wo, W1, W2, Wf,
                                            qkvt, wot, w1t, w2t, wft);
    embed_kernel<<<(M_ * C_ + 255) / 256, 256, 0, stream>>>(x, tok_emb, pos_emb, h);

    for (int l = 0; l < L_; ++l) {
        ln_kernel<<<M_ / 4, 256, 0, stream>>>(h, ln1_g + l * C_, ln1_b + l * C_, z);
        mm_kernel<0, false, false><<<dim3(128, 9), 256, 0, stream>>>(
            z, qkvt + (size_t)l * 1152 * 384, nullptr, big, nullptr, 1152, 384);
        attn_kernel<<<dim3(8, B_ * H_), 256, 0, stream>>>(big, ob);
        mm_kernel<1, false, true><<<dim3(128, 3), 256, 0, stream>>>(
            ob, wot + (size_t)l * 384 * 384, bo + l * C_, nullptr, h, 384, 384);
        ln_kernel<<<M_ / 4, 256, 0, stream>>>(h, ln2_g + l * C_, ln2_b + l * C_, z);
        mm_kernel<0, true, true><<<dim3(128, 12), 256, 0, stream>>>(
            z, w1t + (size_t)l * 1536 * 384, b1 + l * FF_, big, nullptr, 1536, 384);
        mm_kernel<1, false, true><<<dim3(128, 3), 256, 0, stream>>>(
            big, w2t + (size_t)l * 384 * 1536, b2 + l * C_, nullptr, h, 384, 1536);
    }

    ln_kernel<<<M_ / 4, 256, 0, stream>>>(h, lnf_g, lnf_b, z);
    mm_kernel<2, false, true><<<dim3(128, 2), 256, 0, stream>>>(
        z, wft, bf, nullptr, logits, 256, 384);

    nll_kernel<<<M_, 64, 0, stream>>>(logits, targets, nll);
    loss_kernel<<<1, 256, 0, stream>>>(nll, loss);
}

// Round 7
// 1532.550 us; speedup vs baseline: 21.8355x; 1.0082x over previous
//
#include <hip/hip_runtime.h>
#include <hip/hip_bf16.h>
#include <math.h>

// Problem constants
#define B_  16
#define T_  1023
#define C_  384
#define H_  6
#define DH_ 64
#define L_  6
#define V_  256
#define FF_ 1536
#define M_  (B_*T_)      // 16368 rows
#define MP_ 16384        // padded rows (128-multiple)
#define EPS_ 1e-5f

typedef __attribute__((ext_vector_type(8))) short bf16x8;
typedef __attribute__((ext_vector_type(4))) short short4v;
typedef __attribute__((ext_vector_type(4))) float f32x4;

__device__ inline short f2bf(float x) {   // RNE float->bf16
    union { float f; unsigned u; } c; c.f = x;
    unsigned r = (c.u + 0x7fffu + ((c.u >> 16) & 1u)) >> 16;
    return (short)r;
}

#define GLDS16(g, l) __builtin_amdgcn_global_load_lds(                         \
    (const __attribute__((address_space(1))) void*)(g),                        \
    (__attribute__((address_space(3))) void*)(l), 16, 0, 0)

// hardware transpose read: 4 bf16 per lane (rule #18: waitcnt+sched_barrier after)
#define TRRD(dst, va, IMM) asm volatile("ds_read_b64_tr_b16 %0, %1 offset:" IMM \
    : "=v"(dst) : "v"(va))

// ---------------- embedding: h = tok_emb[x] + pos_emb (fp32) ----------------
__global__ void embed_kernel(const int* __restrict__ x, const float* __restrict__ tok,
                             const float* __restrict__ pos, float* __restrict__ h) {
    int i = blockIdx.x * 256 + threadIdx.x;
    if (i >= M_ * C_) return;
    int bt = i / C_;
    int c  = i - bt * C_;
    int t  = bt % T_;
    h[i] = tok[x[bt] * C_ + c] + pos[t * C_ + c];
}

// ---------------- weight transpose+convert: src fp32 [K][N] -> dst bf16 [N][K] ----
__global__ __launch_bounds__(256) void wconv_kernel(
    const float* __restrict__ Wq, const float* __restrict__ Wk,
    const float* __restrict__ Wv, const float* __restrict__ Wo,
    const float* __restrict__ W1, const float* __restrict__ W2,
    const float* __restrict__ Wf,
    short* __restrict__ qkvt, short* __restrict__ wot, short* __restrict__ w1t,
    short* __restrict__ w2t, short* __restrict__ wft) {
    __shared__ float tile[32][33];
    int t = blockIdx.x;
    const float* src; short* dst; int K, N, tl;
    if (t < 10368) {
        int l = t / 1728, r = t - l * 1728;
        if (r < 432) {                 // Wq/Wk/Wv -> fused qkv^T rows
            int which = r / 144; tl = r - which * 144;
            src = (which == 0 ? Wq : which == 1 ? Wk : Wv) + (size_t)l * 384 * 384;
            dst = qkvt + (size_t)l * 1152 * 384 + (size_t)which * 384 * 384;
            K = 384; N = 384;
        } else if (r < 576) {
            tl = r - 432;
            src = Wo + (size_t)l * 384 * 384; dst = wot + (size_t)l * 384 * 384;
            K = 384; N = 384;
        } else if (r < 1152) {
            tl = r - 576;
            src = W1 + (size_t)l * 384 * 1536; dst = w1t + (size_t)l * 1536 * 384;
            K = 384; N = 1536;
        } else {
            tl = r - 1152;
            src = W2 + (size_t)l * 1536 * 384; dst = w2t + (size_t)l * 384 * 1536;
            K = 1536; N = 384;
        }
    } else {
        tl = t - 10368; src = Wf; dst = wft; K = 384; N = 256;
    }
    int ntx = N >> 5;
    int k0 = (tl / ntx) << 5, n0 = (tl % ntx) << 5;
    int rr = threadIdx.x >> 5, cc = threadIdx.x & 31;
#pragma unroll
    for (int p = 0; p < 4; ++p)
        tile[rr + 8 * p][cc] = src[(size_t)(k0 + rr + 8 * p) * N + n0 + cc];
    __syncthreads();
#pragma unroll
    for (int p = 0; p < 4; ++p)
        dst[(size_t)(n0 + rr + 8 * p) * K + k0 + cc] = f2bf(tile[cc][rr + 8 * p]);
}

// ---------------- LayerNorm: fp32 in -> bf16 out, 4 rows per block ----------------
__global__ __launch_bounds__(256) void ln_kernel(const float* __restrict__ in,
                                                 const float* __restrict__ g,
                                                 const float* __restrict__ b,
                                                 short* __restrict__ out) {
    int wave = threadIdx.x >> 6, lane = threadIdx.x & 63;
    int row  = blockIdx.x * 4 + wave;       // M_ = 4092*4 exactly
    const float* rp = in + (size_t)row * C_;
    float v[6];
    float s = 0.f, s2 = 0.f;
#pragma unroll
    for (int i = 0; i < 6; ++i) {
        v[i] = rp[i * 64 + lane];
        s  += v[i];
        s2 += v[i] * v[i];
    }
#pragma unroll
    for (int o = 32; o > 0; o >>= 1) {
        s  += __shfl_xor(s,  o, 64);
        s2 += __shfl_xor(s2, o, 64);
    }
    float mu  = s * (1.0f / C_);
    float var = s2 * (1.0f / C_) - mu * mu;
    float rs  = rsqrtf(var + EPS_);
    short* op = out + (size_t)row * C_;
#pragma unroll
    for (int i = 0; i < 6; ++i) {
        int c = i * 64 + lane;
        op[c] = f2bf((v[i] - mu) * rs * g[c] + b[c]);
    }
}

// ---------------- bf16 MFMA GEMM: depth-2 counted-vmcnt pipeline (T4) ----------------
// A: bf16 [MP_][K]; Bt: bf16 [N][K]. 128x128 tile, BK=32, 4 waves.
// Stage(t+2) issued after compute(t); wait is vmcnt(4) = stage(t+1) complete,
// issued a FULL iteration earlier. Never drain to 0 in the main loop.
template<int MODE, bool RELU, bool HB>
__global__ __launch_bounds__(256) void mm_kernel(const short* __restrict__ A,
                                                 const short* __restrict__ Bt,
                                                 const float* __restrict__ bias,
                                                 short* __restrict__ outb,
                                                 float* __restrict__ outf,
                                                 int N, int K) {
    __shared__ short Al[2][4][128][8];   // [dbuf][k-octet][row][8]
    __shared__ short Bl[2][4][128][8];
    int tid  = threadIdx.x;
    int wave = tid >> 6, lane = tid & 63;
    int kg4 = lane >> 4, r16 = lane & 15;
    int wr = (wave >> 1) * 64, wc = (wave & 1) * 64;
    int row0 = blockIdx.x * 128, col0 = blockIdx.y * 128;

    const short* ga = A  + (size_t)(row0 + (tid & 127)) * K + ((tid >> 7) << 3);
    const short* gb = Bt + (size_t)(col0 + (tid & 127)) * K + ((tid >> 7) << 3);
    short* alds = &Al[0][0][0][0];
    short* blds = &Bl[0][0][0][0];

    f32x4 acc[4][4];
#pragma unroll
    for (int i = 0; i < 4; ++i)
#pragma unroll
        for (int j = 0; j < 4; ++j) { acc[i][j][0]=0.f; acc[i][j][1]=0.f; acc[i][j][2]=0.f; acc[i][j][3]=0.f; }

#define MM_STAGE(BUF)                                                          \
    {                                                                          \
        short* la = alds + (BUF) * 4096 + tid * 8;                             \
        short* lb = blds + (BUF) * 4096 + tid * 8;                             \
        GLDS16(ga, la); GLDS16(ga + 16, la + 2048);                            \
        GLDS16(gb, lb); GLDS16(gb + 16, lb + 2048);                            \
        ga += 32; gb += 32;                                                    \
    }

#define MM_COMPUTE(BUF)                                                        \
    {                                                                          \
        const short* ab = alds + (BUF) * 4096 + kg4 * 1024;                    \
        const short* bb = blds + (BUF) * 4096 + kg4 * 1024;                    \
        bf16x8 av[4], bv[4];                                                   \
        _Pragma("unroll")                                                      \
        for (int i = 0; i < 4; ++i) av[i] = *(const bf16x8*)(ab + (wr + 16*i + r16) * 8); \
        _Pragma("unroll")                                                      \
        for (int j = 0; j < 4; ++j) bv[j] = *(const bf16x8*)(bb + (wc + 16*j + r16) * 8); \
        _Pragma("unroll")                                                      \
        for (int i = 0; i < 4; ++i)                                            \
            _Pragma("unroll")                                                  \
            for (int j = 0; j < 4; ++j)                                        \
                acc[i][j] = __builtin_amdgcn_mfma_f32_16x16x32_bf16(av[i], bv[j], acc[i][j], 0, 0, 0); \
    }

    int NT = K >> 5;                       // >= 12 for all our shapes
    MM_STAGE(0);
    MM_STAGE(1);                           // 8 loads in flight
    asm volatile("s_waitcnt vmcnt(4)" ::: "memory");   // stage(0) landed
    __builtin_amdgcn_s_barrier();
    asm volatile("" ::: "memory");

    for (int t = 0; t < NT - 1; ++t) {
        MM_COMPUTE(t & 1);
        __builtin_amdgcn_s_barrier();      // all waves done reading buf[t&1]
        asm volatile("" ::: "memory");
        if (t + 2 < NT) {
            MM_STAGE(t & 1);               // stage(t+2) into freed buffer
            asm volatile("s_waitcnt vmcnt(4)" ::: "memory");  // stage(t+1) landed
        } else {
            asm volatile("s_waitcnt vmcnt(0)" ::: "memory");  // tail drain
        }
        __builtin_amdgcn_s_barrier();
        asm volatile("" ::: "memory");
    }
    MM_COMPUTE((NT - 1) & 1);
#undef MM_STAGE
#undef MM_COMPUTE

#pragma unroll
    for (int j = 0; j < 4; ++j) {
        int col = col0 + wc + 16 * j + r16;
        float bj = HB ? bias[col] : 0.f;
#pragma unroll
        for (int i = 0; i < 4; ++i) {
#pragma unroll
            for (int rg = 0; rg < 4; ++rg) {
                int row = row0 + wr + 16 * i + 4 * kg4 + rg;
                float v = acc[i][j][rg] + bj;
                if (RELU) v = fmaxf(v, 0.f);
                if (MODE == 0) {
                    outb[(size_t)row * N + col] = f2bf(v);
                } else if (MODE == 1) {
                    outf[(size_t)row * N + col] += v;
                } else {
                    if (row < M_) outf[(size_t)row * N + col] = v;
                }
            }
        }
    }
}

// ---------------- MFMA flash attention v3: paired q-tiles ----------------
// Block handles q-tiles (a, 15-a); one staged K/V tile feeds both accumulators.
// Every block does exactly 34 tile-units of MFMA -> uniform duration.
__device__ __forceinline__ void attn_step(int kt, int qg, int g, int r16,
                                          const char* Kb, unsigned ka, unsigned va,
                                          short (*Pw)[40],
                                          bf16x8 qf0, bf16x8 qf1,
                                          f32x4* o_acc, float& m, float& l) {
    // ---- S^T = K @ Q^T ----
    f32x4 s0, s1;
    s0[0]=0.f;s0[1]=0.f;s0[2]=0.f;s0[3]=0.f;
    s1[0]=0.f;s1[1]=0.f;s1[2]=0.f;s1[3]=0.f;
    bf16x8 a00 = *(const bf16x8*)(Kb + ka);
    bf16x8 a01 = *(const bf16x8*)(Kb + (ka ^ 64u));
    bf16x8 a10 = *(const bf16x8*)(Kb + ka + 2048u);
    bf16x8 a11 = *(const bf16x8*)(Kb + ((ka + 2048u) ^ 64u));
    s0 = __builtin_amdgcn_mfma_f32_16x16x32_bf16(a00, qf0, s0, 0, 0, 0);
    s0 = __builtin_amdgcn_mfma_f32_16x16x32_bf16(a01, qf1, s0, 0, 0, 0);
    s1 = __builtin_amdgcn_mfma_f32_16x16x32_bf16(a10, qf0, s1, 0, 0, 0);
    s1 = __builtin_amdgcn_mfma_f32_16x16x32_bf16(a11, qf1, s1, 0, 0, 0);

    // ---- causal mask + online softmax ----
    int kb0 = kt * 32 + 4 * g;
    float sv[8];
#pragma unroll
    for (int r = 0; r < 4; ++r) {
        sv[r]     = (kb0 + r      <= qg) ? s0[r] * 0.125f : -3e38f;
        sv[4 + r] = (kb0 + 16 + r <= qg) ? s1[r] * 0.125f : -3e38f;
    }
    float pmax = sv[0];
#pragma unroll
    for (int i = 1; i < 8; ++i) pmax = fmaxf(pmax, sv[i]);
    pmax = fmaxf(pmax, __shfl_xor(pmax, 16, 64));
    pmax = fmaxf(pmax, __shfl_xor(pmax, 32, 64));
    float mn   = fmaxf(m, pmax);
    float corr = __expf(m - mn);
    float rs = 0.f;
    short pb[8];
#pragma unroll
    for (int i = 0; i < 8; ++i) {
        float p = __expf(sv[i] - mn);
        rs += p;
        pb[i] = f2bf(p);
    }
    rs += __shfl_xor(rs, 16, 64);
    rs += __shfl_xor(rs, 32, 64);
    l = l * corr + rs;
    m = mn;

    short4v t0w, t1w;
    t0w[0]=pb[0]; t0w[1]=pb[1]; t0w[2]=pb[2]; t0w[3]=pb[3];
    t1w[0]=pb[4]; t1w[1]=pb[5]; t1w[2]=pb[6]; t1w[3]=pb[7];
    *(short4v*)&Pw[r16][4 * g]      = t0w;
    *(short4v*)&Pw[r16][16 + 4 * g] = t1w;

    // ---- PV: transpose reads of V, scale O, MFMA ----
    short4v v0, v1, v2, v3, v4, v5, v6, v7;
    TRRD(v0, va, "0");    TRRD(v1, va, "512");
    TRRD(v2, va, "128");  TRRD(v3, va, "640");
    TRRD(v4, va, "256");  TRRD(v5, va, "768");
    TRRD(v6, va, "384");  TRRD(v7, va, "896");

    bf16x8 pB = *(const bf16x8*)&Pw[r16][8 * g];
#pragma unroll
    for (int d = 0; d < 4; ++d) {
        o_acc[d][0] *= corr; o_acc[d][1] *= corr;
        o_acc[d][2] *= corr; o_acc[d][3] *= corr;
    }
    asm volatile("s_waitcnt lgkmcnt(0)" ::: "memory");
    __builtin_amdgcn_sched_barrier(0);

    bf16x8 av0, av1, av2, av3;
#pragma unroll
    for (int i = 0; i < 4; ++i) {
        av0[i] = v0[i]; av0[i + 4] = v1[i];
        av1[i] = v2[i]; av1[i + 4] = v3[i];
        av2[i] = v4[i]; av2[i + 4] = v5[i];
        av3[i] = v6[i]; av3[i + 4] = v7[i];
    }
    o_acc[0] = __builtin_amdgcn_mfma_f32_16x16x32_bf16(av0, pB, o_acc[0], 0, 0, 0);
    o_acc[1] = __builtin_amdgcn_mfma_f32_16x16x32_bf16(av1, pB, o_acc[1], 0, 0, 0);
    o_acc[2] = __builtin_amdgcn_mfma_f32_16x16x32_bf16(av2, pB, o_acc[2], 0, 0, 0);
    o_acc[3] = __builtin_amdgcn_mfma_f32_16x16x32_bf16(av3, pB, o_acc[3], 0, 0, 0);
}

__global__ __launch_bounds__(256) void attn_kernel(const short* __restrict__ qkv,
                                                   short* __restrict__ o) {
    __shared__ short Kl[32 * 64];          // 4 KB
    __shared__ short Vl[32 * 64];          // 4 KB
    __shared__ short P_lds[4][16][40];     // 5 KB

    int tid  = threadIdx.x;
    int wave = tid >> 6;
    int lane = tid & 63;
    int g    = lane >> 4;
    int r16  = lane & 15;

    int qtA = blockIdx.x;          // 0..7
    int qtB = 15 - qtA;            // 15..8
    int bh = blockIdx.y;
    int b  = bh / H_, hh = bh - b * H_;
    size_t rbase = (size_t)b * T_;
    int qoff = hh * 64;

    int q0A = qtA * 64, q0B = qtB * 64;
    int qgA = q0A + wave * 16 + r16;
    int qgB = q0B + wave * 16 + r16;       // may be 1023 (pad query, never stored)

    const short* qrA = qkv + (rbase + qgA) * 1152 + qoff;
    const short* qrB = qkv + (rbase + qgB) * 1152 + qoff;
    bf16x8 qfA0 = *(const bf16x8*)(qrA + 8 * g);
    bf16x8 qfA1 = *(const bf16x8*)(qrA + 32 + 8 * g);
    bf16x8 qfB0 = *(const bf16x8*)(qrB + 8 * g);
    bf16x8 qfB1 = *(const bf16x8*)(qrB + 32 + 8 * g);

    // staging sources (linear LDS dest = tid*16B; swizzle folded into source)
    int kkey = tid >> 3;
    int koct = (tid & 7) ^ (kkey & 7);
    const short* gk = qkv + (rbase + kkey) * 1152 + qoff + 384 + koct * 8;
    int vkey = 4 * (tid >> 5) + ((tid >> 1) & 3);
    int voct = 2 * ((tid >> 3) & 3) + (tid & 1);
    const short* gv = qkv + (rbase + vkey) * 1152 + qoff + 768 + voct * 8;
    short* lk = Kl + tid * 8;
    short* lv = Vl + tid * 8;

    f32x4 oA[4], oB[4];
#pragma unroll
    for (int d = 0; d < 4; ++d) {
        oA[d][0]=0.f; oA[d][1]=0.f; oA[d][2]=0.f; oA[d][3]=0.f;
        oB[d][0]=0.f; oB[d][1]=0.f; oB[d][2]=0.f; oB[d][3]=0.f;
    }
    float mA = -3e38f, lA = 0.f, mB = -3e38f, lB = 0.f;

    const char* Kb = (const char*)Kl;
    unsigned ka = (unsigned)(r16 * 128 + ((g ^ (r16 & 7)) << 4));
    unsigned va = (unsigned)(size_t)(__attribute__((address_space(3))) short*)Vl
                + 1024u * (unsigned)g + 8u * (unsigned)r16;

    int ktA_hi = (q0A + wave * 16 + 15) >> 5;
    int ktB_hi = (q0B + wave * 16 + 15) >> 5;
    int nkt = 2 * (qtB + 1);

    for (int kt = 0; kt < nkt; ++kt) {
        __syncthreads();                       // prior tile's reads complete
        GLDS16(gk, lk);
        GLDS16(gv, lv);
        gk += 32 * 1152; gv += 32 * 1152;
        __syncthreads();                       // staging complete (vmcnt drained)

        if (kt <= ktB_hi)
            attn_step(kt, qgB, g, r16, Kb, ka, va, P_lds[wave], qfB0, qfB1, oB, mB, lB);
        if (kt <= ktA_hi)
            attn_step(kt, qgA, g, r16, Kb, ka, va, P_lds[wave], qfA0, qfA1, oA, mA, lA);
    }

    // ---- epilogue: direct bf16 writes (lane owns its query; d = 16d+4g+r) ----
    {
        float inv = (lA > 0.f) ? 1.f / lA : 0.f;
        short* orow = o + (rbase + qgA) * C_ + qoff;
#pragma unroll
        for (int d = 0; d < 4; ++d) {
            short4v ov;
#pragma unroll
            for (int r = 0; r < 4; ++r) ov[r] = f2bf(oA[d][r] * inv);
            *(short4v*)(orow + 16 * d + 4 * g) = ov;
        }
    }
    if (qgB < T_) {
        float inv = (lB > 0.f) ? 1.f / lB : 0.f;
        short* orow = o + (rbase + qgB) * C_ + qoff;
#pragma unroll
        for (int d = 0; d < 4; ++d) {
            short4v ov;
#pragma unroll
            for (int r = 0; r < 4; ++r) ov[r] = f2bf(oB[d][r] * inv);
            *(short4v*)(orow + 16 * d + 4 * g) = ov;
        }
    }
}

// ---------------- per-row NLL ----------------
__global__ __launch_bounds__(64) void nll_kernel(const float* __restrict__ logits,
                                                 const int* __restrict__ tgt,
                                                 float* __restrict__ nll) {
    int row  = blockIdx.x;
    int lane = threadIdx.x;
    const float* rp = logits + (size_t)row * V_;
    float v[4];
    float mx = -INFINITY;
#pragma unroll
    for (int i = 0; i < 4; ++i) {
        v[i] = rp[i * 64 + lane];
        mx = fmaxf(mx, v[i]);
    }
#pragma unroll
    for (int o = 32; o > 0; o >>= 1) mx = fmaxf(mx, __shfl_xor(mx, o, 64));
    float s = 0.f;
#pragma unroll
    for (int i = 0; i < 4; ++i) s += expf(v[i] - mx);
#pragma unroll
    for (int o = 32; o > 0; o >>= 1) s += __shfl_xor(s, o, 64);
    if (lane == 0) {
        float lse = mx + logf(s);
        nll[row] = lse - rp[tgt[row]];
    }
}

// ---------------- final deterministic mean reduce ----------------
__global__ __launch_bounds__(256) void loss_kernel(const float* __restrict__ nll,
                                                   float* __restrict__ loss) {
    __shared__ float sm[256];
    float s = 0.f;
    for (int i = threadIdx.x; i < M_; i += 256) s += nll[i];
    sm[threadIdx.x] = s;
    __syncthreads();
    for (int o = 128; o > 0; o >>= 1) {
        if (threadIdx.x < o) sm[threadIdx.x] += sm[threadIdx.x + o];
        __syncthreads();
    }
    if (threadIdx.x == 0) *loss = sm[0] * (1.0f / M_);
}

// ---------------- host launcher ----------------
extern "C" void kernel_launch(void* const* d_in, const int* in_sizes, int n_in,
                              void* d_out, int out_size, void* d_ws, size_t ws_size,
                              hipStream_t stream) {
    const int*   x       = (const int*)d_in[0];
    const int*   targets = (const int*)d_in[1];
    const float* tok_emb = (const float*)d_in[2];
    const float* pos_emb = (const float*)d_in[3];
    const float* Wq      = (const float*)d_in[4];
    const float* Wk      = (const float*)d_in[5];
    const float* Wv      = (const float*)d_in[6];
    const float* Wo      = (const float*)d_in[7];
    const float* bo      = (const float*)d_in[8];
    const float* ln1_g   = (const float*)d_in[9];
    const float* ln1_b   = (const float*)d_in[10];
    const float* ln2_g   = (const float*)d_in[11];
    const float* ln2_b   = (const float*)d_in[12];
    const float* W1      = (const float*)d_in[13];
    const float* b1      = (const float*)d_in[14];
    const float* W2      = (const float*)d_in[15];
    const float* b2      = (const float*)d_in[16];
    const float* lnf_g   = (const float*)d_in[17];
    const float* lnf_b   = (const float*)d_in[18];
    const float* Wf      = (const float*)d_in[19];
    const float* bf      = (const float*)d_in[20];

    float* logits = (float*)d_out;
    float* loss   = logits + (size_t)M_ * V_;

    float* h    = (float*)d_ws;                          // [MP_][C_] fp32
    short* z    = (short*)(h + (size_t)MP_ * C_);        // [MP_][C_] bf16
    short* big  = z + (size_t)MP_ * C_;                  // [MP_][FF_] bf16 (qkv|ff)
    short* ob   = big + (size_t)MP_ * FF_;               // [MP_][C_] bf16
    short* qkvt = ob + (size_t)MP_ * C_;                 // [L][1152][384]
    short* wot  = qkvt + (size_t)L_ * 1152 * 384;        // [L][384][384]
    short* w1t  = wot + (size_t)L_ * 384 * 384;          // [L][1536][384]
    short* w2t  = w1t + (size_t)L_ * 1536 * 384;         // [L][384][1536]
    short* wft  = w2t + (size_t)L_ * 1536 * 384;         // [256][384]
    float* nll  = (float*)(wft + (size_t)256 * 384);     // [M_]

    wconv_kernel<<<10464, 256, 0, stream>>>(Wq, Wk, Wv, Wo, W1, W2, Wf,
                                            qkvt, wot, w1t, w2t, wft);
    embed_kernel<<<(M_ * C_ + 255) / 256, 256, 0, stream>>>(x, tok_emb, pos_emb, h);

    for (int l = 0; l < L_; ++l) {
        ln_kernel<<<M_ / 4, 256, 0, stream>>>(h, ln1_g + l * C_, ln1_b + l * C_, z);
        mm_kernel<0, false, false><<<dim3(128, 9), 256, 0, stream>>>(
            z, qkvt + (size_t)l * 1152 * 384, nullptr, big, nullptr, 1152, 384);
        attn_kernel<<<dim3(8, B_ * H_), 256, 0, stream>>>(big, ob);
        mm_kernel<1, false, true><<<dim3(128, 3), 256, 0, stream>>>(
            ob, wot + (size_t)l * 384 * 384, bo + l * C_, nullptr, h, 384, 384);
        ln_kernel<<<M_ / 4, 256, 0, stream>>>(h, ln2_g + l * C_, ln2_b + l * C_, z);
        mm_kernel<0, true, true><<<dim3(128, 12), 256, 0, stream>>>(
            z, w1t + (size_t)l * 1536 * 384, b1 + l * FF_, big, nullptr, 1536, 384);
        mm_kernel<1, false, true><<<dim3(128, 3), 256, 0, stream>>>(
            big, w2t + (size_t)l * 384 * 1536, b2 + l * C_, nullptr, h, 384, 1536);
    }

    ln_kernel<<<M_ / 4, 256, 0, stream>>>(h, lnf_g, lnf_b, z);
    mm_kernel<2, false, true><<<dim3(128, 2), 256, 0, stream>>>(
        z, wft, bf, nullptr, logits, 256, 384);

    nll_kernel<<<M_, 64, 0, stream>>>(logits, targets, nll);
    loss_kernel<<<1, 256, 0, stream>>>(nll, loss);
}